// Round 4
// baseline (3938.052 us; speedup 1.0000x reference)
//
#include <hip/hip_runtime.h>
#include <hip/hip_bf16.h>
#include <math.h>

// ---------------------------------------------------------------------------
// DNC forward on MI355X.
//   k_detect  : device-side input-dtype detection (f32 vs bf16) + bar zero
//   k_convert : canonicalize all inputs -> internal bf16/f32 buffers
//   k_lstm    : persistent 64-block kernel; layer0(t) & layer1(t-1) pipelined,
//               weights-stationary bf16 MFMA (16x16x32), 33 grid barriers
//   k_xi      : interface GEMM (2048 x 480 x 512) MFMA
//   k_mem     : memory recurrence, 1 block/batch; link in REGISTERS (bf16x4
//               tiles), mem matrix in LDS -> no global round-trips
//   k_tanhy   : tanh([out, rvec]) -> bf16
//   k_out     : output GEMM (2048 x 256 x 768) MFMA -> d_out (dtype per flag)
// ---------------------------------------------------------------------------

typedef __bf16 bf16_t;
typedef __attribute__((ext_vector_type(8))) __bf16 bf16x8;
typedef __attribute__((ext_vector_type(4))) __bf16 bf16x4;
typedef __attribute__((ext_vector_type(4))) float f32x4;

#define B_    64
#define T_    32
#define IN_   256
#define H_    512
#define M_    256
#define W_    64
#define R_    4
#define IFACE_ 471
#define DELTA_ 1e-6f

// ---------------- ws layout (bytes) ----------------
#define OFF_H0SEQ  (0L)
#define SZ_H0SEQ   (32L*64*512*2)
#define OFF_OUTSEQ (OFF_H0SEQ + SZ_H0SEQ)
#define SZ_OUTSEQ  (32L*64*512*2)
#define OFF_H0BUF  (OFF_OUTSEQ + SZ_OUTSEQ)
#define SZ_HBUF    (2L*64*512*2)
#define OFF_H1BUF  (OFF_H0BUF + SZ_HBUF)
#define OFF_XI     (OFF_H1BUF + SZ_HBUF)
#define SZ_XI      (32L*64*480*4)
#define OFF_RVEC   (OFF_XI + SZ_XI)
#define SZ_RVEC    (32L*64*256*4)
#define OFF_YBF    (OFF_RVEC + SZ_RVEC)
#define SZ_YBF     (32L*64*768*2)
#define OFF_BAR    (OFF_YBF + SZ_YBF)
#define SZ_BAR     (256L)                 // bar[2] + flag
#define OFF_XB     (OFF_BAR + SZ_BAR)
#define SZ_XB      (64L*32*256*2)
#define OFF_H0B    (OFF_XB + SZ_XB)
#define SZ_H0B     (2L*64*512*2)
#define OFF_W0     (OFF_H0B + SZ_H0B)
#define SZ_W       (2048L*512*2)
#define OFF_W1     (OFF_W0 + SZ_W)
#define OFF_W2     (OFF_W1 + SZ_W)
#define OFF_W3     (OFF_W2 + SZ_W)
#define OFF_WIF    (OFF_W3 + SZ_W)
#define SZ_WIF     (480L*512*2)
#define OFF_WOUTB  (OFF_WIF + SZ_WIF)
#define SZ_WOUTB   (256L*768*2)
#define OFF_BS0    (OFF_WOUTB + SZ_WOUTB)
#define SZ_BS      (2048L*4)
#define OFF_BS1    (OFF_BS0 + SZ_BS)
#define OFF_BIF    (OFF_BS1 + SZ_BS)
#define SZ_BIF     (2048L)
#define OFF_BOUTF  (OFF_BIF + SZ_BIF)
#define SZ_BOUTF   (1024L)

__device__ __forceinline__ float sigf(float x){ return 1.0f/(1.0f + expf(-x)); }
__device__ __forceinline__ float softplusf(float x){
  return fmaxf(x, 0.0f) + log1pf(expf(-fabsf(x)));
}
__device__ __forceinline__ float wred(float v){
  #pragma unroll
  for (int off = 32; off; off >>= 1) v += __shfl_xor(v, off, 64);
  return v;
}
__device__ __forceinline__ float ldin(const void* p, long i, int mf){
  return mf ? ((const float*)p)[i] : (float)((const bf16_t*)p)[i];
}

// agent-scope generation barrier; all gridDim.x blocks must call
__device__ __forceinline__ void gridbar(unsigned* cnt, unsigned* gen, unsigned nb){
  __syncthreads();
  if (threadIdx.x == 0){
    unsigned g = __hip_atomic_load(gen, __ATOMIC_ACQUIRE, __HIP_MEMORY_SCOPE_AGENT);
    unsigned a = __hip_atomic_fetch_add(cnt, 1u, __ATOMIC_ACQ_REL, __HIP_MEMORY_SCOPE_AGENT);
    if (a == nb - 1u){
      __hip_atomic_store(cnt, 0u, __ATOMIC_RELAXED, __HIP_MEMORY_SCOPE_AGENT);
      __hip_atomic_fetch_add(gen, 1u, __ATOMIC_ACQ_REL, __HIP_MEMORY_SCOPE_AGENT);
    } else {
      while (__hip_atomic_load(gen, __ATOMIC_ACQUIRE, __HIP_MEMORY_SCOPE_AGENT) == g)
        __builtin_amdgcn_s_sleep(2);
    }
  }
  __syncthreads();
}

// ---------------------------------------------------------------------------
__global__ void k_detect(const unsigned short* __restrict__ x16,
                         int* __restrict__ flag, unsigned* __restrict__ bar){
  __shared__ int cnt;
  if (threadIdx.x == 0){ cnt = 0; bar[0] = 0u; bar[1] = 0u; }
  __syncthreads();
  unsigned short u = x16[threadIdx.x * 2];
  int e = (u >> 7) & 0xFF;
  if (e >= 0x88) atomicAdd(&cnt, 1);
  __syncthreads();
  if (threadIdx.x == 0) *flag = (cnt > 16) ? 1 : 0;
}

// ---------------------------------------------------------------------------
__global__ void k_convert(const void* x, const void* h0, const void* Wih0,
                          const void* Whh0, const void* bih0, const void* bhh0,
                          const void* Wih1, const void* Whh1, const void* bih1,
                          const void* bhh1, const void* Wif, const void* bif,
                          const void* Wout, const void* bout,
                          bf16_t* __restrict__ xb, bf16_t* __restrict__ h0b,
                          bf16_t* __restrict__ h0buf, bf16_t* __restrict__ h1buf,
                          bf16_t* __restrict__ W0, bf16_t* __restrict__ W1,
                          bf16_t* __restrict__ W2, bf16_t* __restrict__ W3,
                          bf16_t* __restrict__ Wifp, bf16_t* __restrict__ Woutb,
                          float* __restrict__ bs0, float* __restrict__ bs1,
                          float* __restrict__ bifp, float* __restrict__ boutf,
                          const int* __restrict__ flag)
{
  const int mf = *flag;
  const long stride = (long)gridDim.x * blockDim.x;
  long i0 = (long)blockIdx.x * blockDim.x + threadIdx.x;
  switch (blockIdx.y){
  case 0: for (long i = i0; i < 64L*32*256; i += stride) xb[i] = (bf16_t)ldin(x, i, mf); break;
  case 1: for (long i = i0; i < 2L*64*512; i += stride){
            float v = ldin(h0, i, mf); bf16_t bb = (bf16_t)v; h0b[i] = bb;
            if (i < 64*512) h0buf[i] = bb; else h1buf[i - 64*512] = bb;
          } break;
  case 2: for (long i = i0; i < 2048L*512; i += stride) W0[i] = (bf16_t)ldin(Wih0, i, mf); break;
  case 3: for (long i = i0; i < 2048L*512; i += stride) W1[i] = (bf16_t)ldin(Whh0, i, mf); break;
  case 4: for (long i = i0; i < 2048L*512; i += stride) W2[i] = (bf16_t)ldin(Wih1, i, mf); break;
  case 5: for (long i = i0; i < 2048L*512; i += stride) W3[i] = (bf16_t)ldin(Whh1, i, mf); break;
  case 6: for (long i = i0; i < 480L*512; i += stride){
            long r = i >> 9;
            Wifp[i] = (r < IFACE_) ? (bf16_t)ldin(Wif, i, mf) : (bf16_t)0.0f;
          } break;
  case 7: for (long i = i0; i < 256L*768; i += stride) Woutb[i] = (bf16_t)ldin(Wout, i, mf); break;
  case 8:
    for (long i = i0; i < 2048; i += stride){
      bs0[i] = ldin(bih0, i, mf) + ldin(bhh0, i, mf);
      bs1[i] = ldin(bih1, i, mf) + ldin(bhh1, i, mf);
    }
    for (long i = i0; i < 480; i += stride) bifp[i] = (i < IFACE_) ? ldin(bif, i, mf) : 0.0f;
    for (long i = i0; i < 256; i += stride) boutf[i] = ldin(bout, i, mf);
    break;
  }
}

// ---------------------------------------------------------------------------
// Persistent LSTM.  blocks 0..31: layer0 (units bid*16..+16); 32..63: layer1.
__global__ __launch_bounds__(256,1) void k_lstm(
    const bf16_t* __restrict__ xb, const bf16_t* __restrict__ h0b,
    const bf16_t* __restrict__ W0, const bf16_t* __restrict__ W1,
    const bf16_t* __restrict__ W2, const bf16_t* __restrict__ W3,
    const float* __restrict__ bs0, const float* __restrict__ bs1,
    bf16_t* __restrict__ h0buf, bf16_t* __restrict__ h1buf,
    bf16_t* __restrict__ h0seq, bf16_t* __restrict__ outseq,
    unsigned* __restrict__ bar)
{
  __shared__ float cst[64][16];   // c-state [batch][unit-local]
  __shared__ float bias[4][16];

  const int bid = blockIdx.x;
  const int layer = bid >> 5;
  const int u0 = (bid & 31) * 16;
  const int tid = threadIdx.x;
  const int lane = tid & 63;
  const int wv = tid >> 6;        // 4 waves
  const int m16 = lane & 15, q = lane >> 4;

  for (int i = tid; i < 64*16; i += 256){
    int b = i >> 4, n = i & 15;
    cst[b][n] = (float)h0b[layer*(64*512) + b*512 + u0 + n];  // c init = h init
  }
  if (tid < 64){
    int G = tid >> 4, n = tid & 15;
    const float* bs = layer ? bs1 : bs0;
    bias[G][n] = bs[G*512 + u0 + n];
  }
  __syncthreads();

  const bf16_t* Wi = layer ? W2 : W0;
  const bf16_t* Wh = layer ? W3 : W1;
  bf16_t* hbuf = layer ? h1buf : h0buf;

  for (int ps = 0; ps <= 32; ++ps){
    const int t = layer ? (ps - 1) : ps;
    const bool active = layer ? (ps >= 1) : (ps < 32);
    if (active){
      const int p = t & 1;
      const bf16_t* hin = hbuf + p*(64*512);
      bf16_t* hout = hbuf + (p^1)*(64*512);
      const int b0 = wv * 16;

      f32x4 acc[4];
      #pragma unroll
      for (int G = 0; G < 4; ++G){ float bv = bias[G][m16]; acc[G] = (f32x4){bv,bv,bv,bv}; }

      const int nkt = layer ? 32 : 24;
      for (int kt = 0; kt < nkt; ++kt){
        const bf16_t* asrc;
        const bf16_t* wbase; int kcol;
        if (!layer){
          if (kt < 8){ asrc = xb + ((size_t)(b0+m16)*T_ + t)*IN_ + kt*32 + q*8;
                       wbase = Wi; kcol = kt*32; }
          else       { asrc = hin + (b0+m16)*512 + (kt-8)*32 + q*8;
                       wbase = Wh; kcol = (kt-8)*32; }
        } else {
          if (kt < 16){ asrc = h0seq + ((size_t)t*64 + b0+m16)*512 + kt*32 + q*8;
                        wbase = Wi; kcol = kt*32; }
          else        { asrc = hin + (b0+m16)*512 + (kt-16)*32 + q*8;
                        wbase = Wh; kcol = (kt-16)*32; }
        }
        bf16x8 afrag = *(const bf16x8*)asrc;
        #pragma unroll
        for (int G = 0; G < 4; ++G){
          const bf16_t* bsrc = wbase + (size_t)(G*512 + u0 + m16)*512 + kcol + q*8;
          bf16x8 bfrag = *(const bf16x8*)bsrc;
          acc[G] = __builtin_amdgcn_mfma_f32_16x16x32_bf16(afrag, bfrag, acc[G], 0, 0, 0);
        }
      }
      #pragma unroll
      for (int v = 0; v < 4; ++v){
        int b = b0 + q*4 + v;
        float gi = acc[0][v], gf = acc[1][v], gg = acc[2][v], go = acc[3][v];
        float c_ = sigf(gf)*cst[b][m16] + sigf(gi)*tanhf(gg);
        cst[b][m16] = c_;
        float h = sigf(go)*tanhf(c_);
        bf16_t hb = (bf16_t)h;
        hout[b*512 + u0 + m16] = hb;
        if (!layer) h0seq[((size_t)t*64 + b)*512 + u0 + m16] = hb;
        else        outseq[((size_t)t*64 + b)*512 + u0 + m16] = hb;
      }
    }
    gridbar(bar, bar + 1, gridDim.x);
  }
}

// ---------------------------------------------------------------------------
__global__ __launch_bounds__(256,1) void k_xi(
    const bf16_t* __restrict__ outseq, const bf16_t* __restrict__ Wifp,
    const float* __restrict__ bifp, float* __restrict__ XI)
{
  const int mt = blockIdx.x;            // 0..127
  const int tid = threadIdx.x, lane = tid & 63, wv = tid >> 6;
  const int nt = blockIdx.y*4 + wv;     // 0..31
  if (nt >= 30) return;
  const int m16 = lane & 15, q = lane >> 4;
  const int r = nt*16 + m16;
  float bv = bifp[r];
  f32x4 acc = {bv,bv,bv,bv};
  const bf16_t* arow = outseq + (size_t)(mt*16 + m16)*512 + q*8;
  const bf16_t* brow = Wifp + (size_t)r*512 + q*8;
  for (int kt = 0; kt < 16; ++kt){
    bf16x8 a = *(const bf16x8*)(arow + kt*32);
    bf16x8 bb = *(const bf16x8*)(brow + kt*32);
    acc = __builtin_amdgcn_mfma_f32_16x16x32_bf16(a, bb, acc, 0, 0, 0);
  }
  #pragma unroll
  for (int v = 0; v < 4; ++v){
    int row = mt*16 + q*4 + v;
    XI[(size_t)row*480 + nt*16 + m16] = acc[v];
  }
}

// ---------------------------------------------------------------------------
__device__ __forceinline__ void softmax256_wave(float* a, int lane){
  float v0=a[lane], v1=a[64+lane], v2=a[128+lane], v3=a[192+lane];
  float mx = fmaxf(fmaxf(v0,v1), fmaxf(v2,v3));
  #pragma unroll
  for (int off=32; off; off>>=1) mx = fmaxf(mx, __shfl_xor(mx, off, 64));
  v0=expf(v0-mx); v1=expf(v1-mx); v2=expf(v2-mx); v3=expf(v3-mx);
  float s = v0+v1+v2+v3;
  #pragma unroll
  for (int off=32; off; off>>=1) s += __shfl_xor(s, off, 64);
  float inv = 1.0f/s;
  a[lane]=v0*inv; a[64+lane]=v1*inv; a[128+lane]=v2*inv; a[192+lane]=v3*inv;
}

// one block per batch; 1024 threads = 16 waves.
// Link matrix lives in REGISTERS: thread (wv,lane) owns rows wv*16..+16,
// cols lane*4..+4, stored bf16x4 per row (32 VGPRs). Mem matrix in LDS.
__global__ __launch_bounds__(1024,1) void k_mem(
    const float* __restrict__ XI, float* __restrict__ RVEC)
{
  const int b = blockIdx.x;
  const int tid = threadIdx.x, lane = tid & 63, wv = tid >> 6;

  __shared__ float smem[256][64];   // memory matrix (64 KB)
  __shared__ float xib[480];
  __shared__ float rkn[4][64], wkn[64], ev_[64], wvv[64];
  __shared__ float rs_[4], fg_[4], rm_[4][3];
  __shared__ float wsS, agS, wgS, wwsumS;
  __shared__ float invn[256], wcw[256];
  __shared__ float usage[256], uu[256], alloc_[256], su[256], scanA[256];
  __shared__ int   rank_[256], rnk4[256][4];
  __shared__ float ww_[256], prec_[256];
  __shared__ float rw_[4][256], fwd_[4][256], bwd_[4][256], rcw_[4][256];
  __shared__ float rvl[4][64];

  bf16x4 L[16];                     // my link tile, bf16 (rows wv*16+i, cols lane*4..+4)
  #pragma unroll
  for (int i = 0; i < 16; ++i) L[i] = (bf16x4){(bf16_t)0.f,(bf16_t)0.f,(bf16_t)0.f,(bf16_t)0.f};

  // ---- init state ----
  { int r = tid >> 8, m = tid & 255; rw_[r][m] = DELTA_; }
  if (tid < 256){
    ww_[tid] = DELTA_; usage[tid] = 0.0f; prec_[tid] = 0.0f;
    invn[tid] = 1.0f/(sqrtf(64.0f*DELTA_*DELTA_) + DELTA_);
  }
  for (int i = tid; i < 256*64; i += 1024) ((float*)smem)[i] = DELTA_;
  __syncthreads();

  const int c0 = lane*4;

  for (int t = 0; t < 32; ++t){
    const float* xi = XI + ((size_t)t*64 + b)*480;
    // ---- phase 0: parse interface vector ----
    if (tid < IFACE_) xib[tid] = xi[tid];
    __syncthreads();
    if (wv < 4){                                  // read keys: tanh + normalize
      float v = tanhf(xib[wv*64 + lane]);
      float s = wred(v*v);
      rkn[wv][lane] = v/(sqrtf(s) + DELTA_);
    } else if (wv == 4){                          // write key
      float v = tanhf(xib[260 + lane]);
      float s = wred(v*v);
      wkn[lane] = v/(sqrtf(s) + DELTA_);
    } else if (wv == 5){ ev_[lane] = sigf(xib[325 + lane]);
    } else if (wv == 6){ wvv[lane] = tanhf(xib[389 + lane]);
    } else if (wv == 7){
      if (lane < 4)        rs_[lane] = softplusf(xib[256 + lane]);
      else if (lane == 4)  wsS = softplusf(xib[324]);
      else if (lane < 9)   fg_[lane-5] = sigf(xib[453 + (lane-5)]);
      else if (lane == 9)  agS = sigf(xib[457]);
      else if (lane == 10) wgS = sigf(xib[458]);
      else if (lane >= 16 && lane < 20){
        int r = lane - 16;
        float a0 = xib[459+r*3], a1 = xib[459+r*3+1], a2 = xib[459+r*3+2];
        float mx = fmaxf(a0, fmaxf(a1, a2));
        float e0 = expf(a0-mx), e1 = expf(a1-mx), e2 = expf(a2-mx);
        float s = e0+e1+e2;
        rm_[r][0]=e0/s; rm_[r][1]=e1/s; rm_[r][2]=e2/s;
      }
    }
    __syncthreads();

    // ---- phase 1: usage update (OLD ww, OLD rw) ----
    if (tid < 256){
      int m = tid;
      float us = usage[m] + (1.0f - usage[m])*ww_[m];
      float psi = (1.0f - fg_[0]*rw_[0][m]) * (1.0f - fg_[1]*rw_[1][m])
                * (1.0f - fg_[2]*rw_[2][m]) * (1.0f - fg_[3]*rw_[3][m]);
      us *= psi;
      usage[m] = us;
      uu[m] = DELTA_ + (1.0f - DELTA_)*us;
    }
    __syncthreads();

    // ---- phase 2: write content weights on OLD mem (LDS) ----
    #pragma unroll 1
    for (int i = 0; i < 16; ++i){
      int m = wv*16 + i;
      float s = wred(smem[m][lane] * wkn[lane]);
      if (lane == 0) wcw[m] = wsS * s * invn[m];
    }
    __syncthreads();
    if (wv == 0) softmax256_wave(wcw, lane);
    __syncthreads();

    // ---- phase 3: allocation via stable rank-sort + exclusive cumprod ----
    { int i = tid >> 2, jc = tid & 3;
      float ui = uu[i]; int cnt = 0;
      for (int s = 0; s < 64; ++s){
        int j = s*4 + jc; float uj = uu[j];     // consecutive addrs: conflict-free
        cnt += (uj < ui || (uj == ui && j < i)) ? 1 : 0;
      }
      rnk4[i][jc] = cnt; }
    __syncthreads();
    if (tid < 256){
      int r = rnk4[tid][0] + rnk4[tid][1] + rnk4[tid][2] + rnk4[tid][3];
      rank_[tid] = r;
      su[r] = uu[tid];
    }
    __syncthreads();
    if (wv == 0){   // exclusive product scan of su -> scanA (single wave)
      int base = lane*4;
      float v0 = su[base], v1 = su[base+1], v2 = su[base+2];
      float p1 = v0*v1, p2 = p1*v2, p3 = p2*su[base+3];
      float sc = p3;
      #pragma unroll
      for (int off = 1; off < 64; off <<= 1){
        float n = __shfl_up(sc, off, 64);
        if (lane >= off) sc *= n;
      }
      float exch = __shfl_up(sc, 1, 64);
      if (lane == 0) exch = 1.0f;
      scanA[base] = exch; scanA[base+1] = exch*v0;
      scanA[base+2] = exch*p1; scanA[base+3] = exch*p2;
    }
    __syncthreads();
    if (tid < 256) alloc_[tid] = (1.0f - uu[tid]) * scanA[rank_[tid]];
    __syncthreads();

    // ---- phase 4: write weights + zero bwd ----
    if (tid < 256) ww_[tid] = wgS*(agS*alloc_[tid] + (1.0f - agS)*wcw[tid]);
    { int r = tid >> 8, m = tid & 255; bwd_[r][m] = 0.0f; }
    __syncthreads();
    if (wv == 0){
      float s = wred(ww_[lane] + ww_[64+lane] + ww_[128+lane] + ww_[192+lane]);
      if (lane == 0) wwsumS = s;
    }
    __syncthreads();

    // ---- phase 5: mem erase/write (LDS) + new norms + read-content ----
    #pragma unroll 1
    for (int i = 0; i < 16; ++i){
      int m = wv*16 + i;
      float wm = ww_[m];
      float mn = smem[m][lane]*(1.0f - wm*ev_[lane]) + wm*wvv[lane];
      smem[m][lane] = mn;
      float s = wred(mn*mn);
      float inv = 1.0f/(sqrtf(s) + DELTA_);
      if (lane == 0) invn[m] = inv;
      #pragma unroll
      for (int r = 0; r < 4; ++r){
        float sr = wred(mn * rkn[r][lane]);
        if (lane == 0) rcw_[r][m] = rs_[r]*sr*inv;
      }
    }
    __syncthreads();
    if (wv < 4) softmax256_wave(rcw_[wv], lane);
    __syncthreads();

    // ---- phase 6: link update + fwd + bwd — pure register compute ----
    { float wwv4[4], pv[4], rwc[4][4], bacc[4][4];
      #pragma unroll
      for (int ci = 0; ci < 4; ++ci){ wwv4[ci] = ww_[c0+ci]; pv[ci] = prec_[c0+ci]; }
      #pragma unroll
      for (int r = 0; r < 4; ++r)
        #pragma unroll
        for (int ci = 0; ci < 4; ++ci){ rwc[r][ci] = rw_[r][c0+ci]; bacc[r][ci] = 0.0f; }
      #pragma unroll
      for (int i = 0; i < 16; ++i){
        const int j = wv*16 + i;
        float wj = ww_[j];
        float rwj0 = rw_[0][j], rwj1 = rw_[1][j], rwj2 = rw_[2][j], rwj3 = rw_[3][j];
        float fpart[4] = {0,0,0,0};
        #pragma unroll
        for (int ci = 0; ci < 4; ++ci){
          float Lold = (float)L[i][ci];
          float v = (1.0f - wj - wwv4[ci])*Lold + wj*pv[ci];
          if (c0 + ci == j) v = 0.0f;
          L[i][ci] = (bf16_t)v;
          fpart[0] += v*rwc[0][ci]; fpart[1] += v*rwc[1][ci];
          fpart[2] += v*rwc[2][ci]; fpart[3] += v*rwc[3][ci];
          bacc[0][ci] += rwj0*v; bacc[1][ci] += rwj1*v;
          bacc[2][ci] += rwj2*v; bacc[3][ci] += rwj3*v;
        }
        #pragma unroll
        for (int r = 0; r < 4; ++r){
          float s = wred(fpart[r]);
          if (lane == 0) fwd_[r][j] = s;
        }
      }
      #pragma unroll
      for (int r = 0; r < 4; ++r)
        #pragma unroll
        for (int ci = 0; ci < 4; ++ci)
          atomicAdd(&bwd_[r][c0+ci], bacc[r][ci]);
    }
    __syncthreads();

    // ---- phase 7/9: precedence + new read weights ----
    if (tid < 256) prec_[tid] = (1.0f - wwsumS)*prec_[tid] + ww_[tid];
    { int r = tid >> 8, m = tid & 255;
      rw_[r][m] = rm_[r][0]*bwd_[r][m] + rm_[r][1]*fwd_[r][m] + rm_[r][2]*rcw_[r][m]; }
    __syncthreads();

    // ---- phase 10: read vectors ----
    if (tid < 256) rvl[tid>>6][tid&63] = 0.0f;
    __syncthreads();
    { float racc[4] = {0,0,0,0};
      #pragma unroll 1
      for (int i = 0; i < 16; ++i){
        int m = wv*16 + i;
        float mv = smem[m][lane];
        racc[0] += rw_[0][m]*mv; racc[1] += rw_[1][m]*mv;
        racc[2] += rw_[2][m]*mv; racc[3] += rw_[3][m]*mv;
      }
      #pragma unroll
      for (int r = 0; r < 4; ++r) atomicAdd(&rvl[r][lane], racc[r]); }
    __syncthreads();
    if (tid < 256) RVEC[((size_t)t*64 + b)*256 + tid] = rvl[tid>>6][tid&63];
    __syncthreads();
  }
}

// ---------------------------------------------------------------------------
__global__ void k_tanhy(const bf16_t* __restrict__ outseq, const float* __restrict__ RVEC,
                        bf16_t* __restrict__ Y){
  const int n = 2048*768;
  for (int i = blockIdx.x*blockDim.x + threadIdx.x; i < n; i += gridDim.x*blockDim.x){
    int row = i / 768, j = i - row*768;
    float v = (j < 512) ? (float)outseq[(size_t)row*512 + j] : RVEC[(size_t)row*256 + (j - 512)];
    Y[i] = (bf16_t)tanhf(v);
  }
}

__global__ __launch_bounds__(256,1) void k_out(
    const bf16_t* __restrict__ Y, const bf16_t* __restrict__ Woutb,
    const float* __restrict__ boutf, void* __restrict__ dout,
    const int* __restrict__ flag)
{
  const int mf = *flag;
  const int mt = blockIdx.x;          // 0..127
  const int tid = threadIdx.x, lane = tid & 63, wv = tid >> 6;
  const int nt = blockIdx.y*4 + wv;   // 0..15
  const int m16 = lane & 15, q = lane >> 4;
  const int o = nt*16 + m16;
  float bv = boutf[o];
  f32x4 acc = {bv,bv,bv,bv};
  const bf16_t* arow = Y + (size_t)(mt*16 + m16)*768 + q*8;
  const bf16_t* brow = Woutb + (size_t)o*768 + q*8;
  for (int kt = 0; kt < 24; ++kt){
    acc = __builtin_amdgcn_mfma_f32_16x16x32_bf16(
        *(const bf16x8*)(arow + kt*32), *(const bf16x8*)(brow + kt*32), acc, 0, 0, 0);
  }
  #pragma unroll
  for (int v = 0; v < 4; ++v){
    int row = mt*16 + q*4 + v;        // = t*64 + b
    int b = row & 63, t = row >> 6;
    size_t idx = ((size_t)b*T_ + t)*256 + o;
    if (mf) ((float*)dout)[idx] = acc[v];
    else    ((bf16_t*)dout)[idx] = (bf16_t)acc[v];
  }
}

// ---------------------------------------------------------------------------
extern "C" void kernel_launch(void* const* d_in, const int* in_sizes, int n_in,
                              void* d_out, int out_size, void* d_ws, size_t ws_size,
                              hipStream_t stream)
{
  char* ws = (char*)d_ws;
  bf16_t* H0SEQ  = (bf16_t*)(ws + OFF_H0SEQ);
  bf16_t* OUTSEQ = (bf16_t*)(ws + OFF_OUTSEQ);
  bf16_t* H0BUF  = (bf16_t*)(ws + OFF_H0BUF);
  bf16_t* H1BUF  = (bf16_t*)(ws + OFF_H1BUF);
  float*  XI     = (float*) (ws + OFF_XI);
  float*  RVEC   = (float*) (ws + OFF_RVEC);
  bf16_t* YBF    = (bf16_t*)(ws + OFF_YBF);
  unsigned* BAR  = (unsigned*)(ws + OFF_BAR);
  int*    FLAG   = (int*)   (ws + OFF_BAR + 8);
  bf16_t* XB     = (bf16_t*)(ws + OFF_XB);
  bf16_t* H0B    = (bf16_t*)(ws + OFF_H0B);
  bf16_t* W0     = (bf16_t*)(ws + OFF_W0);
  bf16_t* W1     = (bf16_t*)(ws + OFF_W1);
  bf16_t* W2     = (bf16_t*)(ws + OFF_W2);
  bf16_t* W3     = (bf16_t*)(ws + OFF_W3);
  bf16_t* WIFP   = (bf16_t*)(ws + OFF_WIF);
  bf16_t* WOUTB  = (bf16_t*)(ws + OFF_WOUTB);
  float*  BS0    = (float*) (ws + OFF_BS0);
  float*  BS1    = (float*) (ws + OFF_BS1);
  float*  BIFP   = (float*) (ws + OFF_BIF);
  float*  BOUTF  = (float*) (ws + OFF_BOUTF);

  k_detect<<<1, 256, 0, stream>>>((const unsigned short*)d_in[0], FLAG, BAR);
  k_convert<<<dim3(256, 9), 256, 0, stream>>>(
      d_in[0], d_in[1], d_in[2], d_in[3], d_in[4], d_in[5], d_in[6],
      d_in[7], d_in[8], d_in[9], d_in[10], d_in[11], d_in[12], d_in[13],
      XB, H0B, H0BUF, H1BUF, W0, W1, W2, W3, WIFP, WOUTB,
      BS0, BS1, BIFP, BOUTF, FLAG);
  k_lstm<<<64, 256, 0, stream>>>(XB, H0B, W0, W1, W2, W3, BS0, BS1,
                                 H0BUF, H1BUF, H0SEQ, OUTSEQ, BAR);
  k_xi<<<dim3(128, 8), 256, 0, stream>>>(OUTSEQ, WIFP, BIFP, XI);
  k_mem<<<64, 1024, 0, stream>>>(XI, RVEC);
  k_tanhy<<<512, 256, 0, stream>>>(OUTSEQ, RVEC, YBF);
  k_out<<<dim3(128, 4), 256, 0, stream>>>(YBF, WOUTB, BOUTF, d_out, FLAG);
}

// Round 5
// 3030.335 us; speedup vs baseline: 1.2995x; 1.2995x over previous
//
#include <hip/hip_runtime.h>
#include <hip/hip_bf16.h>
#include <math.h>

// ---------------------------------------------------------------------------
// DNC forward on MI355X.
//   k_detect  : device-side input-dtype detection (f32 vs bf16) + bar zero
//   k_convert : canonicalize all inputs -> internal bf16/f32 buffers
//   k_lstm    : persistent 64-block kernel; layer0(t) & layer1(t-1) pipelined,
//               weights-stationary bf16 MFMA (16x16x32), 33 grid barriers
//   k_xi      : interface GEMM (2048 x 480 x 512) MFMA
//   k_mem     : memory recurrence, 1 block/batch; link in REGISTERS, mem in
//               padded LDS; thread-per-row layouts, no shuffle chains/atomic
//               conflicts on hot paths
//   k_tanhy   : tanh([out, rvec]) -> bf16
//   k_out     : output GEMM (2048 x 256 x 768) MFMA -> d_out (dtype per flag)
// ---------------------------------------------------------------------------

typedef __bf16 bf16_t;
typedef __attribute__((ext_vector_type(8))) __bf16 bf16x8;
typedef __attribute__((ext_vector_type(4))) __bf16 bf16x4;
typedef __attribute__((ext_vector_type(4))) float f32x4;

#define B_    64
#define T_    32
#define IN_   256
#define H_    512
#define M_    256
#define W_    64
#define R_    4
#define IFACE_ 471
#define DELTA_ 1e-6f

// ---------------- ws layout (bytes) ----------------
#define OFF_H0SEQ  (0L)
#define SZ_H0SEQ   (32L*64*512*2)
#define OFF_OUTSEQ (OFF_H0SEQ + SZ_H0SEQ)
#define SZ_OUTSEQ  (32L*64*512*2)
#define OFF_H0BUF  (OFF_OUTSEQ + SZ_OUTSEQ)
#define SZ_HBUF    (2L*64*512*2)
#define OFF_H1BUF  (OFF_H0BUF + SZ_HBUF)
#define OFF_XI     (OFF_H1BUF + SZ_HBUF)
#define SZ_XI      (32L*64*480*4)
#define OFF_RVEC   (OFF_XI + SZ_XI)
#define SZ_RVEC    (32L*64*256*4)
#define OFF_YBF    (OFF_RVEC + SZ_RVEC)
#define SZ_YBF     (32L*64*768*2)
#define OFF_BAR    (OFF_YBF + SZ_YBF)
#define SZ_BAR     (256L)                 // bar[2] + flag
#define OFF_XB     (OFF_BAR + SZ_BAR)
#define SZ_XB      (64L*32*256*2)
#define OFF_H0B    (OFF_XB + SZ_XB)
#define SZ_H0B     (2L*64*512*2)
#define OFF_W0     (OFF_H0B + SZ_H0B)
#define SZ_W       (2048L*512*2)
#define OFF_W1     (OFF_W0 + SZ_W)
#define OFF_W2     (OFF_W1 + SZ_W)
#define OFF_W3     (OFF_W2 + SZ_W)
#define OFF_WIF    (OFF_W3 + SZ_W)
#define SZ_WIF     (480L*512*2)
#define OFF_WOUTB  (OFF_WIF + SZ_WIF)
#define SZ_WOUTB   (256L*768*2)
#define OFF_BS0    (OFF_WOUTB + SZ_WOUTB)
#define SZ_BS      (2048L*4)
#define OFF_BS1    (OFF_BS0 + SZ_BS)
#define OFF_BIF    (OFF_BS1 + SZ_BS)
#define SZ_BIF     (2048L)
#define OFF_BOUTF  (OFF_BIF + SZ_BIF)
#define SZ_BOUTF   (1024L)

__device__ __forceinline__ float sigf(float x){ return 1.0f/(1.0f + expf(-x)); }
__device__ __forceinline__ float softplusf(float x){
  return fmaxf(x, 0.0f) + log1pf(expf(-fabsf(x)));
}
__device__ __forceinline__ float wred(float v){
  #pragma unroll
  for (int off = 32; off; off >>= 1) v += __shfl_xor(v, off, 64);
  return v;
}
__device__ __forceinline__ float ldin(const void* p, long i, int mf){
  return mf ? ((const float*)p)[i] : (float)((const bf16_t*)p)[i];
}

// agent-scope generation barrier; all gridDim.x blocks must call
__device__ __forceinline__ void gridbar(unsigned* cnt, unsigned* gen, unsigned nb){
  __syncthreads();
  if (threadIdx.x == 0){
    unsigned g = __hip_atomic_load(gen, __ATOMIC_ACQUIRE, __HIP_MEMORY_SCOPE_AGENT);
    unsigned a = __hip_atomic_fetch_add(cnt, 1u, __ATOMIC_ACQ_REL, __HIP_MEMORY_SCOPE_AGENT);
    if (a == nb - 1u){
      __hip_atomic_store(cnt, 0u, __ATOMIC_RELAXED, __HIP_MEMORY_SCOPE_AGENT);
      __hip_atomic_fetch_add(gen, 1u, __ATOMIC_ACQ_REL, __HIP_MEMORY_SCOPE_AGENT);
    } else {
      while (__hip_atomic_load(gen, __ATOMIC_ACQUIRE, __HIP_MEMORY_SCOPE_AGENT) == g)
        __builtin_amdgcn_s_sleep(2);
    }
  }
  __syncthreads();
}

// ---------------------------------------------------------------------------
__global__ void k_detect(const unsigned short* __restrict__ x16,
                         int* __restrict__ flag, unsigned* __restrict__ bar){
  __shared__ int cnt;
  if (threadIdx.x == 0){ cnt = 0; bar[0] = 0u; bar[1] = 0u; }
  __syncthreads();
  unsigned short u = x16[threadIdx.x * 2];
  int e = (u >> 7) & 0xFF;
  if (e >= 0x88) atomicAdd(&cnt, 1);
  __syncthreads();
  if (threadIdx.x == 0) *flag = (cnt > 16) ? 1 : 0;
}

// ---------------------------------------------------------------------------
__global__ void k_convert(const void* x, const void* h0, const void* Wih0,
                          const void* Whh0, const void* bih0, const void* bhh0,
                          const void* Wih1, const void* Whh1, const void* bih1,
                          const void* bhh1, const void* Wif, const void* bif,
                          const void* Wout, const void* bout,
                          bf16_t* __restrict__ xb, bf16_t* __restrict__ h0b,
                          bf16_t* __restrict__ h0buf, bf16_t* __restrict__ h1buf,
                          bf16_t* __restrict__ W0, bf16_t* __restrict__ W1,
                          bf16_t* __restrict__ W2, bf16_t* __restrict__ W3,
                          bf16_t* __restrict__ Wifp, bf16_t* __restrict__ Woutb,
                          float* __restrict__ bs0, float* __restrict__ bs1,
                          float* __restrict__ bifp, float* __restrict__ boutf,
                          const int* __restrict__ flag)
{
  const int mf = *flag;
  const long stride = (long)gridDim.x * blockDim.x;
  long i0 = (long)blockIdx.x * blockDim.x + threadIdx.x;
  switch (blockIdx.y){
  case 0: for (long i = i0; i < 64L*32*256; i += stride) xb[i] = (bf16_t)ldin(x, i, mf); break;
  case 1: for (long i = i0; i < 2L*64*512; i += stride){
            float v = ldin(h0, i, mf); bf16_t bb = (bf16_t)v; h0b[i] = bb;
            if (i < 64*512) h0buf[i] = bb; else h1buf[i - 64*512] = bb;
          } break;
  case 2: for (long i = i0; i < 2048L*512; i += stride) W0[i] = (bf16_t)ldin(Wih0, i, mf); break;
  case 3: for (long i = i0; i < 2048L*512; i += stride) W1[i] = (bf16_t)ldin(Whh0, i, mf); break;
  case 4: for (long i = i0; i < 2048L*512; i += stride) W2[i] = (bf16_t)ldin(Wih1, i, mf); break;
  case 5: for (long i = i0; i < 2048L*512; i += stride) W3[i] = (bf16_t)ldin(Whh1, i, mf); break;
  case 6: for (long i = i0; i < 480L*512; i += stride){
            long r = i >> 9;
            Wifp[i] = (r < IFACE_) ? (bf16_t)ldin(Wif, i, mf) : (bf16_t)0.0f;
          } break;
  case 7: for (long i = i0; i < 256L*768; i += stride) Woutb[i] = (bf16_t)ldin(Wout, i, mf); break;
  case 8:
    for (long i = i0; i < 2048; i += stride){
      bs0[i] = ldin(bih0, i, mf) + ldin(bhh0, i, mf);
      bs1[i] = ldin(bih1, i, mf) + ldin(bhh1, i, mf);
    }
    for (long i = i0; i < 480; i += stride) bifp[i] = (i < IFACE_) ? ldin(bif, i, mf) : 0.0f;
    for (long i = i0; i < 256; i += stride) boutf[i] = ldin(bout, i, mf);
    break;
  }
}

// ---------------------------------------------------------------------------
// Persistent LSTM.  blocks 0..31: layer0 (units bid*16..+16); 32..63: layer1.
__global__ __launch_bounds__(256,1) void k_lstm(
    const bf16_t* __restrict__ xb, const bf16_t* __restrict__ h0b,
    const bf16_t* __restrict__ W0, const bf16_t* __restrict__ W1,
    const bf16_t* __restrict__ W2, const bf16_t* __restrict__ W3,
    const float* __restrict__ bs0, const float* __restrict__ bs1,
    bf16_t* __restrict__ h0buf, bf16_t* __restrict__ h1buf,
    bf16_t* __restrict__ h0seq, bf16_t* __restrict__ outseq,
    unsigned* __restrict__ bar)
{
  __shared__ float cst[64][16];   // c-state [batch][unit-local]
  __shared__ float bias[4][16];

  const int bid = blockIdx.x;
  const int layer = bid >> 5;
  const int u0 = (bid & 31) * 16;
  const int tid = threadIdx.x;
  const int lane = tid & 63;
  const int wv = tid >> 6;        // 4 waves
  const int m16 = lane & 15, q = lane >> 4;

  for (int i = tid; i < 64*16; i += 256){
    int b = i >> 4, n = i & 15;
    cst[b][n] = (float)h0b[layer*(64*512) + b*512 + u0 + n];  // c init = h init
  }
  if (tid < 64){
    int G = tid >> 4, n = tid & 15;
    const float* bs = layer ? bs1 : bs0;
    bias[G][n] = bs[G*512 + u0 + n];
  }
  __syncthreads();

  const bf16_t* Wi = layer ? W2 : W0;
  const bf16_t* Wh = layer ? W3 : W1;
  bf16_t* hbuf = layer ? h1buf : h0buf;

  for (int ps = 0; ps <= 32; ++ps){
    const int t = layer ? (ps - 1) : ps;
    const bool active = layer ? (ps >= 1) : (ps < 32);
    if (active){
      const int p = t & 1;
      const bf16_t* hin = hbuf + p*(64*512);
      bf16_t* hout = hbuf + (p^1)*(64*512);
      const int b0 = wv * 16;

      f32x4 acc[4];
      #pragma unroll
      for (int G = 0; G < 4; ++G){ float bv = bias[G][m16]; acc[G] = (f32x4){bv,bv,bv,bv}; }

      const int nkt = layer ? 32 : 24;
      for (int kt = 0; kt < nkt; ++kt){
        const bf16_t* asrc;
        const bf16_t* wbase; int kcol;
        if (!layer){
          if (kt < 8){ asrc = xb + ((size_t)(b0+m16)*T_ + t)*IN_ + kt*32 + q*8;
                       wbase = Wi; kcol = kt*32; }
          else       { asrc = hin + (b0+m16)*512 + (kt-8)*32 + q*8;
                       wbase = Wh; kcol = (kt-8)*32; }
        } else {
          if (kt < 16){ asrc = h0seq + ((size_t)t*64 + b0+m16)*512 + kt*32 + q*8;
                        wbase = Wi; kcol = kt*32; }
          else        { asrc = hin + (b0+m16)*512 + (kt-16)*32 + q*8;
                        wbase = Wh; kcol = (kt-16)*32; }
        }
        bf16x8 afrag = *(const bf16x8*)asrc;
        #pragma unroll
        for (int G = 0; G < 4; ++G){
          const bf16_t* bsrc = wbase + (size_t)(G*512 + u0 + m16)*512 + kcol + q*8;
          bf16x8 bfrag = *(const bf16x8*)bsrc;
          acc[G] = __builtin_amdgcn_mfma_f32_16x16x32_bf16(afrag, bfrag, acc[G], 0, 0, 0);
        }
      }
      #pragma unroll
      for (int v = 0; v < 4; ++v){
        int b = b0 + q*4 + v;
        float gi = acc[0][v], gf = acc[1][v], gg = acc[2][v], go = acc[3][v];
        float c_ = sigf(gf)*cst[b][m16] + sigf(gi)*tanhf(gg);
        cst[b][m16] = c_;
        float h = sigf(go)*tanhf(c_);
        bf16_t hb = (bf16_t)h;
        hout[b*512 + u0 + m16] = hb;
        if (!layer) h0seq[((size_t)t*64 + b)*512 + u0 + m16] = hb;
        else        outseq[((size_t)t*64 + b)*512 + u0 + m16] = hb;
      }
    }
    gridbar(bar, bar + 1, gridDim.x);
  }
}

// ---------------------------------------------------------------------------
__global__ __launch_bounds__(256,1) void k_xi(
    const bf16_t* __restrict__ outseq, const bf16_t* __restrict__ Wifp,
    const float* __restrict__ bifp, float* __restrict__ XI)
{
  const int mt = blockIdx.x;            // 0..127
  const int tid = threadIdx.x, lane = tid & 63, wv = tid >> 6;
  const int nt = blockIdx.y*4 + wv;     // 0..31
  if (nt >= 30) return;
  const int m16 = lane & 15, q = lane >> 4;
  const int r = nt*16 + m16;
  float bv = bifp[r];
  f32x4 acc = {bv,bv,bv,bv};
  const bf16_t* arow = outseq + (size_t)(mt*16 + m16)*512 + q*8;
  const bf16_t* brow = Wifp + (size_t)r*512 + q*8;
  for (int kt = 0; kt < 16; ++kt){
    bf16x8 a = *(const bf16x8*)(arow + kt*32);
    bf16x8 bb = *(const bf16x8*)(brow + kt*32);
    acc = __builtin_amdgcn_mfma_f32_16x16x32_bf16(a, bb, acc, 0, 0, 0);
  }
  #pragma unroll
  for (int v = 0; v < 4; ++v){
    int row = mt*16 + q*4 + v;
    XI[(size_t)row*480 + nt*16 + m16] = acc[v];
  }
}

// ---------------------------------------------------------------------------
__device__ __forceinline__ void softmax256_wave(float* a, int lane){
  float v0=a[lane], v1=a[64+lane], v2=a[128+lane], v3=a[192+lane];
  float mx = fmaxf(fmaxf(v0,v1), fmaxf(v2,v3));
  #pragma unroll
  for (int off=32; off; off>>=1) mx = fmaxf(mx, __shfl_xor(mx, off, 64));
  v0=expf(v0-mx); v1=expf(v1-mx); v2=expf(v2-mx); v3=expf(v3-mx);
  float s = v0+v1+v2+v3;
  #pragma unroll
  for (int off=32; off; off>>=1) s += __shfl_xor(s, off, 64);
  float inv = 1.0f/s;
  a[lane]=v0*inv; a[64+lane]=v1*inv; a[128+lane]=v2*inv; a[192+lane]=v3*inv;
}

// one block per batch; 1024 threads = 16 waves.
// smem[256][65]: pad-65 -> bank (m+w)%32; both row- and column-parallel
// access patterns are conflict-free.  Link matrix in registers: thread
// (wv,lane) owns rows wv*16..+16, cols {lane, lane+64, lane+128, lane+192}.
__global__ __launch_bounds__(1024,1) void k_mem(
    const float* __restrict__ XI, float* __restrict__ RVEC)
{
  const int b = blockIdx.x;
  const int tid = threadIdx.x, lane = tid & 63, wv = tid >> 6;

  __shared__ float smem[256][65];
  __shared__ float xib[480];
  __shared__ float rkn[4][64], wkn[64], ev_[64], wvv[64];
  __shared__ float rs_[4], fg_[4], rm_[4][3];
  __shared__ float wsS, agS, wgS, wwsumS;
  __shared__ float invn[256], wcw[256];
  __shared__ float usage[256], uu[256], alloc_[256], su[256], scanA[256];
  __shared__ int   rank_[256], rnk4[256][4];
  __shared__ float ww_[256], prec_[256];
  __shared__ float rw_[4][256], fwd_[4][256], bwd_[4][256], rcw_[4][256];
  __shared__ float p2c[256][4];      // phase-2 partials
  __shared__ float p5c[256][4][6];   // phase-5 partials: s2, sr[0..3]
  __shared__ float rvp[16][64];      // phase-10 partials

  bf16x4 L[16];   // link tile: row wv*16+i, col lane+64*ci
  #pragma unroll
  for (int i = 0; i < 16; ++i) L[i] = (bf16x4){(bf16_t)0.f,(bf16_t)0.f,(bf16_t)0.f,(bf16_t)0.f};

  // ---- init state ----
  { int r = tid >> 8, m = tid & 255; rw_[r][m] = DELTA_; }
  if (tid < 256){
    ww_[tid] = DELTA_; usage[tid] = 0.0f; prec_[tid] = 0.0f;
    invn[tid] = 1.0f/(sqrtf(64.0f*DELTA_*DELTA_) + DELTA_);
  }
  for (int i = tid; i < 256*65; i += 1024) ((float*)smem)[i] = DELTA_;
  __syncthreads();

  for (int t = 0; t < 32; ++t){
    const float* xi = XI + ((size_t)t*64 + b)*480;
    // ---- phase 0: parse interface vector ----
    if (tid < IFACE_) xib[tid] = xi[tid];
    __syncthreads();
    if (wv < 4){                                  // read keys: tanh + normalize
      float v = tanhf(xib[wv*64 + lane]);
      float s = wred(v*v);
      rkn[wv][lane] = v/(sqrtf(s) + DELTA_);
    } else if (wv == 4){                          // write key
      float v = tanhf(xib[260 + lane]);
      float s = wred(v*v);
      wkn[lane] = v/(sqrtf(s) + DELTA_);
    } else if (wv == 5){ ev_[lane] = sigf(xib[325 + lane]);
    } else if (wv == 6){ wvv[lane] = tanhf(xib[389 + lane]);
    } else if (wv == 7){
      if (lane < 4)        rs_[lane] = softplusf(xib[256 + lane]);
      else if (lane == 4)  wsS = softplusf(xib[324]);
      else if (lane < 9)   fg_[lane-5] = sigf(xib[453 + (lane-5)]);
      else if (lane == 9)  agS = sigf(xib[457]);
      else if (lane == 10) wgS = sigf(xib[458]);
      else if (lane >= 16 && lane < 20){
        int r = lane - 16;
        float a0 = xib[459+r*3], a1 = xib[459+r*3+1], a2 = xib[459+r*3+2];
        float mx = fmaxf(a0, fmaxf(a1, a2));
        float e0 = expf(a0-mx), e1 = expf(a1-mx), e2 = expf(a2-mx);
        float s = e0+e1+e2;
        rm_[r][0]=e0/s; rm_[r][1]=e1/s; rm_[r][2]=e2/s;
      }
    }
    __syncthreads();

    // ---- phase 1: usage update (OLD ww, OLD rw) ----
    if (tid < 256){
      int m = tid;
      float us = usage[m] + (1.0f - usage[m])*ww_[m];
      float psi = (1.0f - fg_[0]*rw_[0][m]) * (1.0f - fg_[1]*rw_[1][m])
                * (1.0f - fg_[2]*rw_[2][m]) * (1.0f - fg_[3]*rw_[3][m]);
      us *= psi;
      usage[m] = us;
      uu[m] = DELTA_ + (1.0f - DELTA_)*us;
    }
    __syncthreads();

    // ---- phase 2: write content sim on OLD mem; thread-per-(row,quarter) ----
    { const int m = tid >> 2, q = tid & 3;
      float acc = 0.0f;
      #pragma unroll
      for (int it = 0; it < 16; ++it){
        int w = q*16 + it;
        acc += smem[m][w] * wkn[w];
      }
      p2c[m][q] = acc; }
    __syncthreads();
    if (tid < 256)
      wcw[tid] = wsS * (p2c[tid][0]+p2c[tid][1]+p2c[tid][2]+p2c[tid][3]) * invn[tid];
    __syncthreads();
    if (wv == 0) softmax256_wave(wcw, lane);
    __syncthreads();

    // ---- phase 3: allocation via stable rank-sort + exclusive cumprod ----
    { int i = tid >> 2, jc = tid & 3;
      float ui = uu[i]; int cnt = 0;
      #pragma unroll
      for (int s = 0; s < 64; ++s){
        int j = s*4 + jc; float uj = uu[j];
        cnt += (uj < ui || (uj == ui && j < i)) ? 1 : 0;
      }
      rnk4[i][jc] = cnt; }
    __syncthreads();
    if (tid < 256){
      int r = rnk4[tid][0] + rnk4[tid][1] + rnk4[tid][2] + rnk4[tid][3];
      rank_[tid] = r;
      su[r] = uu[tid];
    }
    __syncthreads();
    if (wv == 0){   // exclusive product scan of su -> scanA (single wave)
      int base = lane*4;
      float v0 = su[base], v1 = su[base+1], v2 = su[base+2];
      float p1 = v0*v1, p2 = p1*v2, p3 = p2*su[base+3];
      float sc = p3;
      #pragma unroll
      for (int off = 1; off < 64; off <<= 1){
        float n = __shfl_up(sc, off, 64);
        if (lane >= off) sc *= n;
      }
      float exch = __shfl_up(sc, 1, 64);
      if (lane == 0) exch = 1.0f;
      scanA[base] = exch; scanA[base+1] = exch*v0;
      scanA[base+2] = exch*p1; scanA[base+3] = exch*p2;
    }
    __syncthreads();
    if (tid < 256) alloc_[tid] = (1.0f - uu[tid]) * scanA[rank_[tid]];
    __syncthreads();

    // ---- phase 4: write weights + zero bwd ----
    if (tid < 256) ww_[tid] = wgS*(agS*alloc_[tid] + (1.0f - agS)*wcw[tid]);
    { int r = tid >> 8, m = tid & 255; bwd_[r][m] = 0.0f; }
    __syncthreads();
    if (wv == 0){
      float s = wred(ww_[lane] + ww_[64+lane] + ww_[128+lane] + ww_[192+lane]);
      if (lane == 0) wwsumS = s;
    }
    __syncthreads();

    // ---- phase 5: mem erase/write + norms + read-content; thread-per-(row,quarter) ----
    { const int m = tid >> 2, q = tid & 3;
      const float wm = ww_[m];
      float s2 = 0.0f, sr0 = 0.0f, sr1 = 0.0f, sr2 = 0.0f, sr3 = 0.0f;
      #pragma unroll
      for (int it = 0; it < 16; ++it){
        int w = q*16 + it;
        float mn = smem[m][w]*(1.0f - wm*ev_[w]) + wm*wvv[w];
        smem[m][w] = mn;
        s2  += mn*mn;
        sr0 += mn*rkn[0][w]; sr1 += mn*rkn[1][w];
        sr2 += mn*rkn[2][w]; sr3 += mn*rkn[3][w];
      }
      p5c[m][q][0] = s2;
      p5c[m][q][1] = sr0; p5c[m][q][2] = sr1;
      p5c[m][q][3] = sr2; p5c[m][q][4] = sr3; }
    __syncthreads();
    if (tid < 256){
      int m = tid;
      float s2 = p5c[m][0][0]+p5c[m][1][0]+p5c[m][2][0]+p5c[m][3][0];
      float inv = 1.0f/(sqrtf(s2) + DELTA_);
      invn[m] = inv;
      #pragma unroll
      for (int r = 0; r < 4; ++r){
        float sr = p5c[m][0][r+1]+p5c[m][1][r+1]+p5c[m][2][r+1]+p5c[m][3][r+1];
        rcw_[r][m] = rs_[r]*sr*inv;
      }
    }
    __syncthreads();
    if (wv < 4) softmax256_wave(rcw_[wv], lane);
    __syncthreads();

    // ---- phase 6: link update + fwd + bwd (register link, stride-64 cols) ----
    { float wwv4[4], pv[4], rwc[4][4], bacc[4][4];
      #pragma unroll
      for (int ci = 0; ci < 4; ++ci){
        wwv4[ci] = ww_[lane + 64*ci]; pv[ci] = prec_[lane + 64*ci];
      }
      #pragma unroll
      for (int r = 0; r < 4; ++r)
        #pragma unroll
        for (int ci = 0; ci < 4; ++ci){ rwc[r][ci] = rw_[r][lane + 64*ci]; bacc[r][ci] = 0.0f; }
      #pragma unroll
      for (int i = 0; i < 16; ++i){
        const int j = wv*16 + i;
        float wj = ww_[j];
        float rwj0 = rw_[0][j], rwj1 = rw_[1][j], rwj2 = rw_[2][j], rwj3 = rw_[3][j];
        float fpart[4] = {0,0,0,0};
        #pragma unroll
        for (int ci = 0; ci < 4; ++ci){
          float Lold = (float)L[i][ci];
          float v = (1.0f - wj - wwv4[ci])*Lold + wj*pv[ci];
          if (lane + 64*ci == j) v = 0.0f;
          L[i][ci] = (bf16_t)v;
          fpart[0] += v*rwc[0][ci]; fpart[1] += v*rwc[1][ci];
          fpart[2] += v*rwc[2][ci]; fpart[3] += v*rwc[3][ci];
          bacc[0][ci] += rwj0*v; bacc[1][ci] += rwj1*v;
          bacc[2][ci] += rwj2*v; bacc[3][ci] += rwj3*v;
        }
        #pragma unroll
        for (int r = 0; r < 4; ++r){
          float s = wred(fpart[r]);
          if (lane == 0) fwd_[r][j] = s;
        }
      }
      #pragma unroll
      for (int r = 0; r < 4; ++r)
        #pragma unroll
        for (int ci = 0; ci < 4; ++ci)
          atomicAdd(&bwd_[r][lane + 64*ci], bacc[r][ci]);   // stride-1: conflict-free
    }
    __syncthreads();

    // ---- phase 7/9: precedence + new read weights ----
    if (tid < 256) prec_[tid] = (1.0f - wwsumS)*prec_[tid] + ww_[tid];
    { int r = tid >> 8, m = tid & 255;
      rw_[r][m] = rm_[r][0]*bwd_[r][m] + rm_[r][1]*fwd_[r][m] + rm_[r][2]*rcw_[r][m]; }
    __syncthreads();

    // ---- phase 10: read vectors; thread-per-(r,w,chunk) column partials ----
    { const int w = tid & 63, rc = tid >> 6;       // rc = c*4 + r
      const int r = rc & 3, c = rc >> 2;
      float racc = 0.0f;
      #pragma unroll
      for (int k = 0; k < 64; ++k){
        int m = c*64 + k;
        racc += rw_[r][m] * smem[m][w];
      }
      rvp[rc][w] = racc; }
    __syncthreads();
    if (tid < 256){
      const int w = tid & 63, r = tid >> 6;
      float v = rvp[r][w] + rvp[4+r][w] + rvp[8+r][w] + rvp[12+r][w];
      RVEC[((size_t)t*64 + b)*256 + tid] = v;
    }
    __syncthreads();
  }
}

// ---------------------------------------------------------------------------
__global__ void k_tanhy(const bf16_t* __restrict__ outseq, const float* __restrict__ RVEC,
                        bf16_t* __restrict__ Y){
  const int n = 2048*768;
  for (int i = blockIdx.x*blockDim.x + threadIdx.x; i < n; i += gridDim.x*blockDim.x){
    int row = i / 768, j = i - row*768;
    float v = (j < 512) ? (float)outseq[(size_t)row*512 + j] : RVEC[(size_t)row*256 + (j - 512)];
    Y[i] = (bf16_t)tanhf(v);
  }
}

__global__ __launch_bounds__(256,1) void k_out(
    const bf16_t* __restrict__ Y, const bf16_t* __restrict__ Woutb,
    const float* __restrict__ boutf, void* __restrict__ dout,
    const int* __restrict__ flag)
{
  const int mf = *flag;
  const int mt = blockIdx.x;          // 0..127
  const int tid = threadIdx.x, lane = tid & 63, wv = tid >> 6;
  const int nt = blockIdx.y*4 + wv;   // 0..15
  const int m16 = lane & 15, q = lane >> 4;
  const int o = nt*16 + m16;
  float bv = boutf[o];
  f32x4 acc = {bv,bv,bv,bv};
  const bf16_t* arow = Y + (size_t)(mt*16 + m16)*768 + q*8;
  const bf16_t* brow = Woutb + (size_t)o*768 + q*8;
  for (int kt = 0; kt < 24; ++kt){
    acc = __builtin_amdgcn_mfma_f32_16x16x32_bf16(
        *(const bf16x8*)(arow + kt*32), *(const bf16x8*)(brow + kt*32), acc, 0, 0, 0);
  }
  #pragma unroll
  for (int v = 0; v < 4; ++v){
    int row = mt*16 + q*4 + v;        // = t*64 + b
    int b = row & 63, t = row >> 6;
    size_t idx = ((size_t)b*T_ + t)*256 + o;
    if (mf) ((float*)dout)[idx] = acc[v];
    else    ((bf16_t*)dout)[idx] = (bf16_t)acc[v];
  }
}

// ---------------------------------------------------------------------------
extern "C" void kernel_launch(void* const* d_in, const int* in_sizes, int n_in,
                              void* d_out, int out_size, void* d_ws, size_t ws_size,
                              hipStream_t stream)
{
  char* ws = (char*)d_ws;
  bf16_t* H0SEQ  = (bf16_t*)(ws + OFF_H0SEQ);
  bf16_t* OUTSEQ = (bf16_t*)(ws + OFF_OUTSEQ);
  bf16_t* H0BUF  = (bf16_t*)(ws + OFF_H0BUF);
  bf16_t* H1BUF  = (bf16_t*)(ws + OFF_H1BUF);
  float*  XI     = (float*) (ws + OFF_XI);
  float*  RVEC   = (float*) (ws + OFF_RVEC);
  bf16_t* YBF    = (bf16_t*)(ws + OFF_YBF);
  unsigned* BAR  = (unsigned*)(ws + OFF_BAR);
  int*    FLAG   = (int*)   (ws + OFF_BAR + 8);
  bf16_t* XB     = (bf16_t*)(ws + OFF_XB);
  bf16_t* H0B    = (bf16_t*)(ws + OFF_H0B);
  bf16_t* W0     = (bf16_t*)(ws + OFF_W0);
  bf16_t* W1     = (bf16_t*)(ws + OFF_W1);
  bf16_t* W2     = (bf16_t*)(ws + OFF_W2);
  bf16_t* W3     = (bf16_t*)(ws + OFF_W3);
  bf16_t* WIFP   = (bf16_t*)(ws + OFF_WIF);
  bf16_t* WOUTB  = (bf16_t*)(ws + OFF_WOUTB);
  float*  BS0    = (float*) (ws + OFF_BS0);
  float*  BS1    = (float*) (ws + OFF_BS1);
  float*  BIFP   = (float*) (ws + OFF_BIF);
  float*  BOUTF  = (float*) (ws + OFF_BOUTF);

  k_detect<<<1, 256, 0, stream>>>((const unsigned short*)d_in[0], FLAG, BAR);
  k_convert<<<dim3(256, 9), 256, 0, stream>>>(
      d_in[0], d_in[1], d_in[2], d_in[3], d_in[4], d_in[5], d_in[6],
      d_in[7], d_in[8], d_in[9], d_in[10], d_in[11], d_in[12], d_in[13],
      XB, H0B, H0BUF, H1BUF, W0, W1, W2, W3, WIFP, WOUTB,
      BS0, BS1, BIFP, BOUTF, FLAG);
  k_lstm<<<64, 256, 0, stream>>>(XB, H0B, W0, W1, W2, W3, BS0, BS1,
                                 H0BUF, H1BUF, H0SEQ, OUTSEQ, BAR);
  k_xi<<<dim3(128, 8), 256, 0, stream>>>(OUTSEQ, WIFP, BIFP, XI);
  k_mem<<<64, 1024, 0, stream>>>(XI, RVEC);
  k_tanhy<<<512, 256, 0, stream>>>(OUTSEQ, RVEC, YBF);
  k_out<<<dim3(128, 4), 256, 0, stream>>>(YBF, WOUTB, BOUTF, d_out, FLAG);
}

// Round 6
// 1871.447 us; speedup vs baseline: 2.1043x; 1.6192x over previous
//
#include <hip/hip_runtime.h>
#include <hip/hip_bf16.h>
#include <math.h>

// ---------------------------------------------------------------------------
// DNC forward on MI355X.
//   k_detect  : device-side input-dtype detection (f32 vs bf16) + bar zero
//   k_convert : canonicalize all inputs -> internal bf16/f32 buffers
//   k_lstm    : persistent 64-block kernel; layer0(t) & layer1(t-1) pipelined,
//               weights-stationary bf16 MFMA (16x16x32), 33 grid barriers
//   k_xi      : interface GEMM (2048 x 480 x 512) MFMA
//   k_mem     : memory recurrence, 1 block/batch; link kept in REGISTERS in
//               MFMA fragment layouts (row-copy=A-frag, col-copy=B-frag);
//               fwd/bwd via MFMA; mem matrix in padded LDS
//   k_tanhy   : tanh([out, rvec]) -> bf16
//   k_out     : output GEMM (2048 x 256 x 768) MFMA -> d_out (dtype per flag)
// ---------------------------------------------------------------------------

typedef __bf16 bf16_t;
typedef __attribute__((ext_vector_type(8))) __bf16 bf16x8;
typedef __attribute__((ext_vector_type(4))) float f32x4;

#define B_    64
#define T_    32
#define IN_   256
#define H_    512
#define M_    256
#define W_    64
#define R_    4
#define IFACE_ 471
#define DELTA_ 1e-6f

// ---------------- ws layout (bytes) ----------------
#define OFF_H0SEQ  (0L)
#define SZ_H0SEQ   (32L*64*512*2)
#define OFF_OUTSEQ (OFF_H0SEQ + SZ_H0SEQ)
#define SZ_OUTSEQ  (32L*64*512*2)
#define OFF_H0BUF  (OFF_OUTSEQ + SZ_OUTSEQ)
#define SZ_HBUF    (2L*64*512*2)
#define OFF_H1BUF  (OFF_H0BUF + SZ_HBUF)
#define OFF_XI     (OFF_H1BUF + SZ_HBUF)
#define SZ_XI      (32L*64*480*4)
#define OFF_RVEC   (OFF_XI + SZ_XI)
#define SZ_RVEC    (32L*64*256*4)
#define OFF_YBF    (OFF_RVEC + SZ_RVEC)
#define SZ_YBF     (32L*64*768*2)
#define OFF_BAR    (OFF_YBF + SZ_YBF)
#define SZ_BAR     (256L)                 // bar[2] + flag
#define OFF_XB     (OFF_BAR + SZ_BAR)
#define SZ_XB      (64L*32*256*2)
#define OFF_H0B    (OFF_XB + SZ_XB)
#define SZ_H0B     (2L*64*512*2)
#define OFF_W0     (OFF_H0B + SZ_H0B)
#define SZ_W       (2048L*512*2)
#define OFF_W1     (OFF_W0 + SZ_W)
#define OFF_W2     (OFF_W1 + SZ_W)
#define OFF_W3     (OFF_W2 + SZ_W)
#define OFF_WIF    (OFF_W3 + SZ_W)
#define SZ_WIF     (480L*512*2)
#define OFF_WOUTB  (OFF_WIF + SZ_WIF)
#define SZ_WOUTB   (256L*768*2)
#define OFF_BS0    (OFF_WOUTB + SZ_WOUTB)
#define SZ_BS      (2048L*4)
#define OFF_BS1    (OFF_BS0 + SZ_BS)
#define OFF_BIF    (OFF_BS1 + SZ_BS)
#define SZ_BIF     (2048L)
#define OFF_BOUTF  (OFF_BIF + SZ_BIF)
#define SZ_BOUTF   (1024L)

__device__ __forceinline__ float sigf(float x){ return 1.0f/(1.0f + expf(-x)); }
__device__ __forceinline__ float softplusf(float x){
  return fmaxf(x, 0.0f) + log1pf(expf(-fabsf(x)));
}
__device__ __forceinline__ float wred(float v){
  #pragma unroll
  for (int off = 32; off; off >>= 1) v += __shfl_xor(v, off, 64);
  return v;
}
__device__ __forceinline__ float ldin(const void* p, long i, int mf){
  return mf ? ((const float*)p)[i] : (float)((const bf16_t*)p)[i];
}

// agent-scope generation barrier; all gridDim.x blocks must call
__device__ __forceinline__ void gridbar(unsigned* cnt, unsigned* gen, unsigned nb){
  __syncthreads();
  if (threadIdx.x == 0){
    unsigned g = __hip_atomic_load(gen, __ATOMIC_ACQUIRE, __HIP_MEMORY_SCOPE_AGENT);
    unsigned a = __hip_atomic_fetch_add(cnt, 1u, __ATOMIC_ACQ_REL, __HIP_MEMORY_SCOPE_AGENT);
    if (a == nb - 1u){
      __hip_atomic_store(cnt, 0u, __ATOMIC_RELAXED, __HIP_MEMORY_SCOPE_AGENT);
      __hip_atomic_fetch_add(gen, 1u, __ATOMIC_ACQ_REL, __HIP_MEMORY_SCOPE_AGENT);
    } else {
      while (__hip_atomic_load(gen, __ATOMIC_ACQUIRE, __HIP_MEMORY_SCOPE_AGENT) == g)
        __builtin_amdgcn_s_sleep(2);
    }
  }
  __syncthreads();
}

// ---------------------------------------------------------------------------
__global__ void k_detect(const unsigned short* __restrict__ x16,
                         int* __restrict__ flag, unsigned* __restrict__ bar){
  __shared__ int cnt;
  if (threadIdx.x == 0){ cnt = 0; bar[0] = 0u; bar[1] = 0u; }
  __syncthreads();
  unsigned short u = x16[threadIdx.x * 2];
  int e = (u >> 7) & 0xFF;
  if (e >= 0x88) atomicAdd(&cnt, 1);
  __syncthreads();
  if (threadIdx.x == 0) *flag = (cnt > 16) ? 1 : 0;
}

// ---------------------------------------------------------------------------
__global__ void k_convert(const void* x, const void* h0, const void* Wih0,
                          const void* Whh0, const void* bih0, const void* bhh0,
                          const void* Wih1, const void* Whh1, const void* bih1,
                          const void* bhh1, const void* Wif, const void* bif,
                          const void* Wout, const void* bout,
                          bf16_t* __restrict__ xb, bf16_t* __restrict__ h0b,
                          bf16_t* __restrict__ h0buf, bf16_t* __restrict__ h1buf,
                          bf16_t* __restrict__ W0, bf16_t* __restrict__ W1,
                          bf16_t* __restrict__ W2, bf16_t* __restrict__ W3,
                          bf16_t* __restrict__ Wifp, bf16_t* __restrict__ Woutb,
                          float* __restrict__ bs0, float* __restrict__ bs1,
                          float* __restrict__ bifp, float* __restrict__ boutf,
                          const int* __restrict__ flag)
{
  const int mf = *flag;
  const long stride = (long)gridDim.x * blockDim.x;
  long i0 = (long)blockIdx.x * blockDim.x + threadIdx.x;
  switch (blockIdx.y){
  case 0: for (long i = i0; i < 64L*32*256; i += stride) xb[i] = (bf16_t)ldin(x, i, mf); break;
  case 1: for (long i = i0; i < 2L*64*512; i += stride){
            float v = ldin(h0, i, mf); bf16_t bb = (bf16_t)v; h0b[i] = bb;
            if (i < 64*512) h0buf[i] = bb; else h1buf[i - 64*512] = bb;
          } break;
  case 2: for (long i = i0; i < 2048L*512; i += stride) W0[i] = (bf16_t)ldin(Wih0, i, mf); break;
  case 3: for (long i = i0; i < 2048L*512; i += stride) W1[i] = (bf16_t)ldin(Whh0, i, mf); break;
  case 4: for (long i = i0; i < 2048L*512; i += stride) W2[i] = (bf16_t)ldin(Wih1, i, mf); break;
  case 5: for (long i = i0; i < 2048L*512; i += stride) W3[i] = (bf16_t)ldin(Whh1, i, mf); break;
  case 6: for (long i = i0; i < 480L*512; i += stride){
            long r = i >> 9;
            Wifp[i] = (r < IFACE_) ? (bf16_t)ldin(Wif, i, mf) : (bf16_t)0.0f;
          } break;
  case 7: for (long i = i0; i < 256L*768; i += stride) Woutb[i] = (bf16_t)ldin(Wout, i, mf); break;
  case 8:
    for (long i = i0; i < 2048; i += stride){
      bs0[i] = ldin(bih0, i, mf) + ldin(bhh0, i, mf);
      bs1[i] = ldin(bih1, i, mf) + ldin(bhh1, i, mf);
    }
    for (long i = i0; i < 480; i += stride) bifp[i] = (i < IFACE_) ? ldin(bif, i, mf) : 0.0f;
    for (long i = i0; i < 256; i += stride) boutf[i] = ldin(bout, i, mf);
    break;
  }
}

// ---------------------------------------------------------------------------
// Persistent LSTM.  blocks 0..31: layer0 (units bid*16..+16); 32..63: layer1.
__global__ __launch_bounds__(256,1) void k_lstm(
    const bf16_t* __restrict__ xb, const bf16_t* __restrict__ h0b,
    const bf16_t* __restrict__ W0, const bf16_t* __restrict__ W1,
    const bf16_t* __restrict__ W2, const bf16_t* __restrict__ W3,
    const float* __restrict__ bs0, const float* __restrict__ bs1,
    bf16_t* __restrict__ h0buf, bf16_t* __restrict__ h1buf,
    bf16_t* __restrict__ h0seq, bf16_t* __restrict__ outseq,
    unsigned* __restrict__ bar)
{
  __shared__ float cst[64][16];   // c-state [batch][unit-local]
  __shared__ float bias[4][16];

  const int bid = blockIdx.x;
  const int layer = bid >> 5;
  const int u0 = (bid & 31) * 16;
  const int tid = threadIdx.x;
  const int lane = tid & 63;
  const int wv = tid >> 6;        // 4 waves
  const int m16 = lane & 15, q = lane >> 4;

  for (int i = tid; i < 64*16; i += 256){
    int b = i >> 4, n = i & 15;
    cst[b][n] = (float)h0b[layer*(64*512) + b*512 + u0 + n];  // c init = h init
  }
  if (tid < 64){
    int G = tid >> 4, n = tid & 15;
    const float* bs = layer ? bs1 : bs0;
    bias[G][n] = bs[G*512 + u0 + n];
  }
  __syncthreads();

  const bf16_t* Wi = layer ? W2 : W0;
  const bf16_t* Wh = layer ? W3 : W1;
  bf16_t* hbuf = layer ? h1buf : h0buf;

  for (int ps = 0; ps <= 32; ++ps){
    const int t = layer ? (ps - 1) : ps;
    const bool active = layer ? (ps >= 1) : (ps < 32);
    if (active){
      const int p = t & 1;
      const bf16_t* hin = hbuf + p*(64*512);
      bf16_t* hout = hbuf + (p^1)*(64*512);
      const int b0 = wv * 16;

      f32x4 acc[4];
      #pragma unroll
      for (int G = 0; G < 4; ++G){ float bv = bias[G][m16]; acc[G] = (f32x4){bv,bv,bv,bv}; }

      const int nkt = layer ? 32 : 24;
      for (int kt = 0; kt < nkt; ++kt){
        const bf16_t* asrc;
        const bf16_t* wbase; int kcol;
        if (!layer){
          if (kt < 8){ asrc = xb + ((size_t)(b0+m16)*T_ + t)*IN_ + kt*32 + q*8;
                       wbase = Wi; kcol = kt*32; }
          else       { asrc = hin + (b0+m16)*512 + (kt-8)*32 + q*8;
                       wbase = Wh; kcol = (kt-8)*32; }
        } else {
          if (kt < 16){ asrc = h0seq + ((size_t)t*64 + b0+m16)*512 + kt*32 + q*8;
                        wbase = Wi; kcol = kt*32; }
          else        { asrc = hin + (b0+m16)*512 + (kt-16)*32 + q*8;
                        wbase = Wh; kcol = (kt-16)*32; }
        }
        bf16x8 afrag = *(const bf16x8*)asrc;
        #pragma unroll
        for (int G = 0; G < 4; ++G){
          const bf16_t* bsrc = wbase + (size_t)(G*512 + u0 + m16)*512 + kcol + q*8;
          bf16x8 bfrag = *(const bf16x8*)bsrc;
          acc[G] = __builtin_amdgcn_mfma_f32_16x16x32_bf16(afrag, bfrag, acc[G], 0, 0, 0);
        }
      }
      #pragma unroll
      for (int v = 0; v < 4; ++v){
        int b = b0 + q*4 + v;
        float gi = acc[0][v], gf = acc[1][v], gg = acc[2][v], go = acc[3][v];
        float c_ = sigf(gf)*cst[b][m16] + sigf(gi)*tanhf(gg);
        cst[b][m16] = c_;
        float h = sigf(go)*tanhf(c_);
        bf16_t hb = (bf16_t)h;
        hout[b*512 + u0 + m16] = hb;
        if (!layer) h0seq[((size_t)t*64 + b)*512 + u0 + m16] = hb;
        else        outseq[((size_t)t*64 + b)*512 + u0 + m16] = hb;
      }
    }
    gridbar(bar, bar + 1, gridDim.x);
  }
}

// ---------------------------------------------------------------------------
__global__ __launch_bounds__(256,1) void k_xi(
    const bf16_t* __restrict__ outseq, const bf16_t* __restrict__ Wifp,
    const float* __restrict__ bifp, float* __restrict__ XI)
{
  const int mt = blockIdx.x;            // 0..127
  const int tid = threadIdx.x, lane = tid & 63, wv = tid >> 6;
  const int nt = blockIdx.y*4 + wv;     // 0..31
  if (nt >= 30) return;
  const int m16 = lane & 15, q = lane >> 4;
  const int r = nt*16 + m16;
  float bv = bifp[r];
  f32x4 acc = {bv,bv,bv,bv};
  const bf16_t* arow = outseq + (size_t)(mt*16 + m16)*512 + q*8;
  const bf16_t* brow = Wifp + (size_t)r*512 + q*8;
  for (int kt = 0; kt < 16; ++kt){
    bf16x8 a = *(const bf16x8*)(arow + kt*32);
    bf16x8 bb = *(const bf16x8*)(brow + kt*32);
    acc = __builtin_amdgcn_mfma_f32_16x16x32_bf16(a, bb, acc, 0, 0, 0);
  }
  #pragma unroll
  for (int v = 0; v < 4; ++v){
    int row = mt*16 + q*4 + v;
    XI[(size_t)row*480 + nt*16 + m16] = acc[v];
  }
}

// ---------------------------------------------------------------------------
__device__ __forceinline__ void softmax256_wave(float* a, int lane){
  float v0=a[lane], v1=a[64+lane], v2=a[128+lane], v3=a[192+lane];
  float mx = fmaxf(fmaxf(v0,v1), fmaxf(v2,v3));
  #pragma unroll
  for (int off=32; off; off>>=1) mx = fmaxf(mx, __shfl_xor(mx, off, 64));
  v0=expf(v0-mx); v1=expf(v1-mx); v2=expf(v2-mx); v3=expf(v3-mx);
  float s = v0+v1+v2+v3;
  #pragma unroll
  for (int off=32; off; off>>=1) s += __shfl_xor(s, off, 64);
  float inv = 1.0f/s;
  a[lane]=v0*inv; a[64+lane]=v1*inv; a[128+lane]=v2*inv; a[192+lane]=v3*inv;
}

// one block per batch; 1024 threads = 16 waves.
// Link matrix: TWO register copies in MFMA fragment layouts (bf16):
//   rowL (A-frag): lane(quad,li) holds link[wv*16+li][ch*32+quad*8 .. +8]
//   colL (B-frag): lane(quad,li) holds link[ch*32+quad*8 .. +8][wv*16+li]
// fwd = Lnew * rw^T  -> mfma(rowL, rwfrag);  bwd = rw * Lnew -> mfma(rwfrag, colL)
__global__ __launch_bounds__(1024,1) void k_mem(
    const float* __restrict__ XI, float* __restrict__ RVEC)
{
  const int b = blockIdx.x;
  const int tid = threadIdx.x, lane = tid & 63, wv = tid >> 6;
  const int quad = lane >> 4, li = lane & 15;

  __shared__ float smem[256][65];      // memory matrix
  __shared__ float xib[480];
  __shared__ float rkn4r[4][65][4];    // [copy q][w][r] replicated, padded
  __shared__ float wkn[64], ev_[64], wvv[64];
  __shared__ float rs_[4], fg_[4], rm_[4][3];
  __shared__ float wsS, agS, wgS, wwsumS;
  __shared__ float invn[256], wcw[256];
  __shared__ float usage[256], uu[256], su[256], scanA[256];
  __shared__ int   rank_[256];
  __shared__ float ww_[256], prec_[256];
  __shared__ float rw_[4][256];
  __shared__ float rw4[256][4];        // packed new rw for phase 10
  __shared__ float fwd_[4][256], bwd_[4][256], rcw_[4][256];
  __shared__ bf16_t rwb[4][264];       // bf16 rw (old) for MFMA frags
  __shared__ bf16_t wwb[256], precb[256];
  __shared__ float p2c[256][4];
  __shared__ float p5c[256][4][5];
  __shared__ float rvp[16][4][64];

  bf16x8 rowL[8], colL[8];
  #pragma unroll
  for (int ch = 0; ch < 8; ++ch){
    #pragma unroll
    for (int z = 0; z < 8; ++z){ rowL[ch][z] = (bf16_t)0.0f; colL[ch][z] = (bf16_t)0.0f; }
  }

  // ---- init state ----
  { int r = tid >> 8, m = tid & 255; rw_[r][m] = DELTA_; }
  if (tid < 256){
    ww_[tid] = DELTA_; usage[tid] = 0.0f; prec_[tid] = 0.0f;
    invn[tid] = 1.0f/(sqrtf(64.0f*DELTA_*DELTA_) + DELTA_);
    wwb[tid] = (bf16_t)DELTA_; precb[tid] = (bf16_t)0.0f;
  }
  for (int i = tid; i < 4*264; i += 1024) ((bf16_t*)rwb)[i] = (bf16_t)DELTA_;
  for (int i = tid; i < 256*65; i += 1024) ((float*)smem)[i] = DELTA_;
  __syncthreads();

  const int own = wv*16 + li;          // my link row (rowL) == my link col (colL)

  for (int t = 0; t < 32; ++t){
    // ---- R1: load interface vector ----
    const float* xi = XI + ((size_t)t*64 + b)*480;
    if (tid < IFACE_) xib[tid] = xi[tid];
    __syncthreads();

    // ---- R2: parse ----
    if (wv < 4){                                  // read keys: tanh + normalize
      float v = tanhf(xib[wv*64 + lane]);
      float s = wred(v*v);
      float vn = v/(sqrtf(s) + DELTA_);
      #pragma unroll
      for (int c = 0; c < 4; ++c) rkn4r[c][lane][wv] = vn;
    } else if (wv == 4){                          // write key
      float v = tanhf(xib[260 + lane]);
      float s = wred(v*v);
      wkn[lane] = v/(sqrtf(s) + DELTA_);
    } else if (wv == 5){ ev_[lane] = sigf(xib[325 + lane]);
    } else if (wv == 6){ wvv[lane] = tanhf(xib[389 + lane]);
    } else if (wv == 7){
      if (lane < 4)        rs_[lane] = softplusf(xib[256 + lane]);
      else if (lane == 4)  wsS = softplusf(xib[324]);
      else if (lane < 9)   fg_[lane-5] = sigf(xib[453 + (lane-5)]);
      else if (lane == 9)  agS = sigf(xib[457]);
      else if (lane == 10) wgS = sigf(xib[458]);
      else if (lane >= 16 && lane < 20){
        int r = lane - 16;
        float a0 = xib[459+r*3], a1 = xib[459+r*3+1], a2 = xib[459+r*3+2];
        float mx = fmaxf(a0, fmaxf(a1, a2));
        float e0 = expf(a0-mx), e1 = expf(a1-mx), e2 = expf(a2-mx);
        float s = e0+e1+e2;
        rm_[r][0]=e0/s; rm_[r][1]=e1/s; rm_[r][2]=e2/s;
      }
    }
    __syncthreads();

    // ---- R3: usage update (tid<256) + write-content partials (all) ----
    if (tid < 256){
      int m = tid;
      float us = usage[m] + (1.0f - usage[m])*ww_[m];
      float psi = (1.0f - fg_[0]*rw_[0][m]) * (1.0f - fg_[1]*rw_[1][m])
                * (1.0f - fg_[2]*rw_[2][m]) * (1.0f - fg_[3]*rw_[3][m]);
      us *= psi;
      usage[m] = us;
      uu[m] = DELTA_ + (1.0f - DELTA_)*us;
    }
    { const int m = tid >> 2, q = tid & 3;
      float acc = 0.0f;
      #pragma unroll
      for (int it = 0; it < 16; ++it){
        int w = q*16 + it;
        acc += smem[m][w] * wkn[w];
      }
      p2c[m][q] = acc; }
    __syncthreads();

    // ---- R4: wave0: wcw combine + softmax ; waves4-7: full rank-sort ----
    if (wv == 0){
      #pragma unroll
      for (int z = 0; z < 4; ++z){
        int m = z*64 + lane;
        f32x4 p = *(const f32x4*)&p2c[m][0];
        wcw[m] = wsS * (p[0]+p[1]+p[2]+p[3]) * invn[m];
      }
      softmax256_wave(wcw, lane);
    } else if (tid >= 256 && tid < 512){
      const int i = tid - 256;
      const float ui = uu[i];
      int cnt = 0;
      #pragma unroll
      for (int k = 0; k < 64; ++k){
        f32x4 u4 = *(const f32x4*)&uu[k*4];
        #pragma unroll
        for (int z = 0; z < 4; ++z){
          int j = k*4 + z; float uj = u4[z];
          cnt += (uj < ui || (uj == ui && j < i)) ? 1 : 0;
        }
      }
      rank_[i] = cnt;
      su[cnt] = ui;
    }
    __syncthreads();

    // ---- R5: exclusive product scan of su -> scanA (wave 0) ----
    if (wv == 0){
      int base = lane*4;
      float v0 = su[base], v1 = su[base+1], v2 = su[base+2];
      float p1 = v0*v1, p2 = p1*v2, p3 = p2*su[base+3];
      float sc = p3;
      #pragma unroll
      for (int off = 1; off < 64; off <<= 1){
        float n = __shfl_up(sc, off, 64);
        if (lane >= off) sc *= n;
      }
      float exch = __shfl_up(sc, 1, 64);
      if (lane == 0) exch = 1.0f;
      scanA[base] = exch; scanA[base+1] = exch*v0;
      scanA[base+2] = exch*p1; scanA[base+3] = exch*p2;
    }
    __syncthreads();

    // ---- R6: write weights (tid<256) ----
    if (tid < 256){
      float al = (1.0f - uu[tid]) * scanA[rank_[tid]];
      float w = wgS*(agS*al + (1.0f - agS)*wcw[tid]);
      ww_[tid] = w;
      wwb[tid] = (bf16_t)w;
    }
    __syncthreads();

    // ---- R7: wave0: wwsum (first); all: mem erase/write + partials ----
    if (wv == 0){
      float s = wred(ww_[lane] + ww_[64+lane] + ww_[128+lane] + ww_[192+lane]);
      if (lane == 0) wwsumS = s;
    }
    { const int m = tid >> 2, q = tid & 3;
      const float wm = ww_[m];
      float s2 = 0.0f, sr0 = 0.0f, sr1 = 0.0f, sr2 = 0.0f, sr3 = 0.0f;
      #pragma unroll
      for (int it = 0; it < 16; ++it){
        int w = q*16 + it;
        float mn = smem[m][w]*(1.0f - wm*ev_[w]) + wm*wvv[w];
        smem[m][w] = mn;
        s2 += mn*mn;
        f32x4 rk = *(const f32x4*)&rkn4r[q][w][0];
        sr0 += mn*rk[0]; sr1 += mn*rk[1]; sr2 += mn*rk[2]; sr3 += mn*rk[3];
      }
      p5c[m][q][0] = s2;
      p5c[m][q][1] = sr0; p5c[m][q][2] = sr1;
      p5c[m][q][3] = sr2; p5c[m][q][4] = sr3; }
    __syncthreads();

    // ---- R8: norm + read-content pre-softmax (tid<256) ----
    if (tid < 256){
      int m = tid;
      float s2 = p5c[m][0][0]+p5c[m][1][0]+p5c[m][2][0]+p5c[m][3][0];
      float inv = 1.0f/(sqrtf(s2) + DELTA_);
      invn[m] = inv;
      #pragma unroll
      for (int r = 0; r < 4; ++r){
        float sr = p5c[m][0][r+1]+p5c[m][1][r+1]+p5c[m][2][r+1]+p5c[m][3][r+1];
        rcw_[r][m] = rs_[r]*sr*inv;
      }
    }
    __syncthreads();

    // ---- R9: link update + fwd/bwd via MFMA (all waves) ----
    { const float wown = (float)wwb[own];
      const float pown = (float)precb[own];
      f32x4 facc = {0,0,0,0}, bacc = {0,0,0,0};
      #pragma unroll
      for (int ch = 0; ch < 8; ++ch){
        const int cbase = ch*32 + quad*8;
        bf16x8 rwf = *(const bf16x8*)&rwb[li & 3][cbase];
        bf16x8 wwv = *(const bf16x8*)&wwb[cbase];
        bf16x8 pcv = *(const bf16x8*)&precb[cbase];
        bf16x8 rl = rowL[ch];
        bf16x8 cl = colL[ch];
        #pragma unroll
        for (int jj = 0; jj < 8; ++jj){
          const int c = cbase + jj;
          float wc = (float)wwv[jj];          // ww of col c (row-copy) == ww of row c (col-copy)
          float pc = (float)pcv[jj];          // prec of col c
          float vr = (1.0f - wown - wc)*(float)rl[jj] + wown*pc;
          float vc = (1.0f - wc - wown)*(float)cl[jj] + wc*pown;
          if (c == own){ vr = 0.0f; vc = 0.0f; }
          rl[jj] = (bf16_t)vr;
          cl[jj] = (bf16_t)vc;
        }
        rowL[ch] = rl; colL[ch] = cl;
        facc = __builtin_amdgcn_mfma_f32_16x16x32_bf16(rl, rwf, facc, 0, 0, 0);
        bacc = __builtin_amdgcn_mfma_f32_16x16x32_bf16(rwf, cl, bacc, 0, 0, 0);
      }
      if (li < 4){
        #pragma unroll
        for (int g = 0; g < 4; ++g) fwd_[li][wv*16 + quad*4 + g] = facc[g];
      }
      if (quad == 0){
        #pragma unroll
        for (int g = 0; g < 4; ++g) bwd_[g][wv*16 + li] = bacc[g];
      }
    }
    __syncthreads();

    // ---- R10: waves0-3: rcw softmax ; threads 256..511: precedence ----
    if (wv < 4) softmax256_wave(rcw_[wv], lane);
    else if (tid >= 256 && tid < 512){
      int m = tid - 256;
      float p = (1.0f - wwsumS)*prec_[m] + ww_[m];
      prec_[m] = p;
      precb[m] = (bf16_t)p;
    }
    __syncthreads();

    // ---- R11: new read weights (all threads) ----
    { int r = tid >> 8, m = tid & 255;
      float v = rm_[r][0]*bwd_[r][m] + rm_[r][1]*fwd_[r][m] + rm_[r][2]*rcw_[r][m];
      rw_[r][m] = v;
      rw4[m][r] = v;
      if (m < 264) rwb[r][m] = (bf16_t)v; }
    __syncthreads();

    // ---- R12: read vectors: wave-per-16-rows, broadcast rw4 ----
    { const int c = wv;
      float r0 = 0, r1 = 0, r2 = 0, r3 = 0;
      #pragma unroll
      for (int k = 0; k < 16; ++k){
        int m = c*16 + k;
        f32x4 r4 = *(const f32x4*)&rw4[m][0];
        float mv = smem[m][lane];
        r0 += r4[0]*mv; r1 += r4[1]*mv; r2 += r4[2]*mv; r3 += r4[3]*mv;
      }
      rvp[c][0][lane] = r0; rvp[c][1][lane] = r1;
      rvp[c][2][lane] = r2; rvp[c][3][lane] = r3; }
    __syncthreads();

    // ---- R13: combine + store ----
    if (tid < 256){
      const int w = tid & 63, r = tid >> 6;
      float v = 0.0f;
      #pragma unroll
      for (int c = 0; c < 16; ++c) v += rvp[c][r][w];
      RVEC[((size_t)t*64 + b)*256 + tid] = v;
    }
    __syncthreads();
  }
}

// ---------------------------------------------------------------------------
__global__ void k_tanhy(const bf16_t* __restrict__ outseq, const float* __restrict__ RVEC,
                        bf16_t* __restrict__ Y){
  const int n = 2048*768;
  for (int i = blockIdx.x*blockDim.x + threadIdx.x; i < n; i += gridDim.x*blockDim.x){
    int row = i / 768, j = i - row*768;
    float v = (j < 512) ? (float)outseq[(size_t)row*512 + j] : RVEC[(size_t)row*256 + (j - 512)];
    Y[i] = (bf16_t)tanhf(v);
  }
}

__global__ __launch_bounds__(256,1) void k_out(
    const bf16_t* __restrict__ Y, const bf16_t* __restrict__ Woutb,
    const float* __restrict__ boutf, void* __restrict__ dout,
    const int* __restrict__ flag)
{
  const int mf = *flag;
  const int mt = blockIdx.x;          // 0..127
  const int tid = threadIdx.x, lane = tid & 63, wv = tid >> 6;
  const int nt = blockIdx.y*4 + wv;   // 0..15
  const int m16 = lane & 15, q = lane >> 4;
  const int o = nt*16 + m16;
  float bv = boutf[o];
  f32x4 acc = {bv,bv,bv,bv};
  const bf16_t* arow = Y + (size_t)(mt*16 + m16)*768 + q*8;
  const bf16_t* brow = Woutb + (size_t)o*768 + q*8;
  for (int kt = 0; kt < 24; ++kt){
    acc = __builtin_amdgcn_mfma_f32_16x16x32_bf16(
        *(const bf16x8*)(arow + kt*32), *(const bf16x8*)(brow + kt*32), acc, 0, 0, 0);
  }
  #pragma unroll
  for (int v = 0; v < 4; ++v){
    int row = mt*16 + q*4 + v;        // = t*64 + b
    int b = row & 63, t = row >> 6;
    size_t idx = ((size_t)b*T_ + t)*256 + o;
    if (mf) ((float*)dout)[idx] = acc[v];
    else    ((bf16_t*)dout)[idx] = (bf16_t)acc[v];
  }
}

// ---------------------------------------------------------------------------
extern "C" void kernel_launch(void* const* d_in, const int* in_sizes, int n_in,
                              void* d_out, int out_size, void* d_ws, size_t ws_size,
                              hipStream_t stream)
{
  char* ws = (char*)d_ws;
  bf16_t* H0SEQ  = (bf16_t*)(ws + OFF_H0SEQ);
  bf16_t* OUTSEQ = (bf16_t*)(ws + OFF_OUTSEQ);
  bf16_t* H0BUF  = (bf16_t*)(ws + OFF_H0BUF);
  bf16_t* H1BUF  = (bf16_t*)(ws + OFF_H1BUF);
  float*  XI     = (float*) (ws + OFF_XI);
  float*  RVEC   = (float*) (ws + OFF_RVEC);
  bf16_t* YBF    = (bf16_t*)(ws + OFF_YBF);
  unsigned* BAR  = (unsigned*)(ws + OFF_BAR);
  int*    FLAG   = (int*)   (ws + OFF_BAR + 8);
  bf16_t* XB     = (bf16_t*)(ws + OFF_XB);
  bf16_t* H0B    = (bf16_t*)(ws + OFF_H0B);
  bf16_t* W0     = (bf16_t*)(ws + OFF_W0);
  bf16_t* W1     = (bf16_t*)(ws + OFF_W1);
  bf16_t* W2     = (bf16_t*)(ws + OFF_W2);
  bf16_t* W3     = (bf16_t*)(ws + OFF_W3);
  bf16_t* WIFP   = (bf16_t*)(ws + OFF_WIF);
  bf16_t* WOUTB  = (bf16_t*)(ws + OFF_WOUTB);
  float*  BS0    = (float*) (ws + OFF_BS0);
  float*  BS1    = (float*) (ws + OFF_BS1);
  float*  BIFP   = (float*) (ws + OFF_BIF);
  float*  BOUTF  = (float*) (ws + OFF_BOUTF);

  k_detect<<<1, 256, 0, stream>>>((const unsigned short*)d_in[0], FLAG, BAR);
  k_convert<<<dim3(256, 9), 256, 0, stream>>>(
      d_in[0], d_in[1], d_in[2], d_in[3], d_in[4], d_in[5], d_in[6],
      d_in[7], d_in[8], d_in[9], d_in[10], d_in[11], d_in[12], d_in[13],
      XB, H0B, H0BUF, H1BUF, W0, W1, W2, W3, WIFP, WOUTB,
      BS0, BS1, BIFP, BOUTF, FLAG);
  k_lstm<<<64, 256, 0, stream>>>(XB, H0B, W0, W1, W2, W3, BS0, BS1,
                                 H0BUF, H1BUF, H0SEQ, OUTSEQ, BAR);
  k_xi<<<dim3(128, 8), 256, 0, stream>>>(OUTSEQ, WIFP, BIFP, XI);
  k_mem<<<64, 1024, 0, stream>>>(XI, RVEC);
  k_tanhy<<<512, 256, 0, stream>>>(OUTSEQ, RVEC, YBF);
  k_out<<<dim3(128, 4), 256, 0, stream>>>(YBF, WOUTB, BOUTF, d_out, FLAG);
}

// Round 7
// 1241.394 us; speedup vs baseline: 3.1723x; 1.5075x over previous
//
#include <hip/hip_runtime.h>
#include <hip/hip_bf16.h>
#include <math.h>

// ---------------------------------------------------------------------------
// DNC forward on MI355X.
//   k_detect  : device-side input-dtype detection (f32 vs bf16) + bar zero
//   k_convert : canonicalize all inputs -> internal bf16/f32 buffers
//   k_lstm    : persistent 64-block kernel; weights staged in LDS once;
//               layer0(t) & layer1(t-1) pipelined; 33 grid barriers
//   k_xi      : interface GEMM (2048 x 480 x 512) MFMA
//   k_mem     : memory recurrence, 1 block/batch, 512 thr (8 waves) so the
//               2x link register tiles (128 VGPR) stay resident (no spill);
//               fwd/bwd via MFMA; mem matrix in padded LDS
//   k_tanhy   : tanh([out, rvec]) -> bf16
//   k_out     : output GEMM (2048 x 256 x 768) MFMA -> d_out (dtype per flag)
// ---------------------------------------------------------------------------

typedef __bf16 bf16_t;
typedef __attribute__((ext_vector_type(8))) __bf16 bf16x8;
typedef __attribute__((ext_vector_type(4))) float f32x4;

#define B_    64
#define T_    32
#define IN_   256
#define H_    512
#define M_    256
#define W_    64
#define R_    4
#define IFACE_ 471
#define DELTA_ 1e-6f

// ---------------- ws layout (bytes) ----------------
#define OFF_H0SEQ  (0L)
#define SZ_H0SEQ   (32L*64*512*2)
#define OFF_OUTSEQ (OFF_H0SEQ + SZ_H0SEQ)
#define SZ_OUTSEQ  (32L*64*512*2)
#define OFF_H0BUF  (OFF_OUTSEQ + SZ_OUTSEQ)
#define SZ_HBUF    (2L*64*512*2)
#define OFF_H1BUF  (OFF_H0BUF + SZ_HBUF)
#define OFF_XI     (OFF_H1BUF + SZ_HBUF)
#define SZ_XI      (32L*64*480*4)
#define OFF_RVEC   (OFF_XI + SZ_XI)
#define SZ_RVEC    (32L*64*256*4)
#define OFF_YBF    (OFF_RVEC + SZ_RVEC)
#define SZ_YBF     (32L*64*768*2)
#define OFF_BAR    (OFF_YBF + SZ_YBF)
#define SZ_BAR     (256L)                 // bar[2] + flag
#define OFF_XB     (OFF_BAR + SZ_BAR)
#define SZ_XB      (64L*32*256*2)
#define OFF_H0B    (OFF_XB + SZ_XB)
#define SZ_H0B     (2L*64*512*2)
#define OFF_W0     (OFF_H0B + SZ_H0B)
#define SZ_W       (2048L*512*2)
#define OFF_W1     (OFF_W0 + SZ_W)
#define OFF_W2     (OFF_W1 + SZ_W)
#define OFF_W3     (OFF_W2 + SZ_W)
#define OFF_WIF    (OFF_W3 + SZ_W)
#define SZ_WIF     (480L*512*2)
#define OFF_WOUTB  (OFF_WIF + SZ_WIF)
#define SZ_WOUTB   (256L*768*2)
#define OFF_BS0    (OFF_WOUTB + SZ_WOUTB)
#define SZ_BS      (2048L*4)
#define OFF_BS1    (OFF_BS0 + SZ_BS)
#define OFF_BIF    (OFF_BS1 + SZ_BS)
#define SZ_BIF     (2048L)
#define OFF_BOUTF  (OFF_BIF + SZ_BIF)
#define SZ_BOUTF   (1024L)

__device__ __forceinline__ float sigf(float x){ return 1.0f/(1.0f + expf(-x)); }
__device__ __forceinline__ float softplusf(float x){
  return fmaxf(x, 0.0f) + log1pf(expf(-fabsf(x)));
}
__device__ __forceinline__ float wred(float v){
  #pragma unroll
  for (int off = 32; off; off >>= 1) v += __shfl_xor(v, off, 64);
  return v;
}
__device__ __forceinline__ float ldin(const void* p, long i, int mf){
  return mf ? ((const float*)p)[i] : (float)((const bf16_t*)p)[i];
}

// agent-scope generation barrier; all gridDim.x blocks must call
__device__ __forceinline__ void gridbar(unsigned* cnt, unsigned* gen, unsigned nb){
  __syncthreads();
  if (threadIdx.x == 0){
    unsigned g = __hip_atomic_load(gen, __ATOMIC_ACQUIRE, __HIP_MEMORY_SCOPE_AGENT);
    unsigned a = __hip_atomic_fetch_add(cnt, 1u, __ATOMIC_ACQ_REL, __HIP_MEMORY_SCOPE_AGENT);
    if (a == nb - 1u){
      __hip_atomic_store(cnt, 0u, __ATOMIC_RELAXED, __HIP_MEMORY_SCOPE_AGENT);
      __hip_atomic_fetch_add(gen, 1u, __ATOMIC_ACQ_REL, __HIP_MEMORY_SCOPE_AGENT);
    } else {
      while (__hip_atomic_load(gen, __ATOMIC_ACQUIRE, __HIP_MEMORY_SCOPE_AGENT) == g)
        __builtin_amdgcn_s_sleep(2);
    }
  }
  __syncthreads();
}

// ---------------------------------------------------------------------------
__global__ void k_detect(const unsigned short* __restrict__ x16,
                         int* __restrict__ flag, unsigned* __restrict__ bar){
  __shared__ int cnt;
  if (threadIdx.x == 0){ cnt = 0; bar[0] = 0u; bar[1] = 0u; }
  __syncthreads();
  unsigned short u = x16[threadIdx.x * 2];
  int e = (u >> 7) & 0xFF;
  if (e >= 0x88) atomicAdd(&cnt, 1);
  __syncthreads();
  if (threadIdx.x == 0) *flag = (cnt > 16) ? 1 : 0;
}

// ---------------------------------------------------------------------------
__global__ void k_convert(const void* x, const void* h0, const void* Wih0,
                          const void* Whh0, const void* bih0, const void* bhh0,
                          const void* Wih1, const void* Whh1, const void* bih1,
                          const void* bhh1, const void* Wif, const void* bif,
                          const void* Wout, const void* bout,
                          bf16_t* __restrict__ xb, bf16_t* __restrict__ h0b,
                          bf16_t* __restrict__ h0buf, bf16_t* __restrict__ h1buf,
                          bf16_t* __restrict__ W0, bf16_t* __restrict__ W1,
                          bf16_t* __restrict__ W2, bf16_t* __restrict__ W3,
                          bf16_t* __restrict__ Wifp, bf16_t* __restrict__ Woutb,
                          float* __restrict__ bs0, float* __restrict__ bs1,
                          float* __restrict__ bifp, float* __restrict__ boutf,
                          const int* __restrict__ flag)
{
  const int mf = *flag;
  const long stride = (long)gridDim.x * blockDim.x;
  long i0 = (long)blockIdx.x * blockDim.x + threadIdx.x;
  switch (blockIdx.y){
  case 0: for (long i = i0; i < 64L*32*256; i += stride) xb[i] = (bf16_t)ldin(x, i, mf); break;
  case 1: for (long i = i0; i < 2L*64*512; i += stride){
            float v = ldin(h0, i, mf); bf16_t bb = (bf16_t)v; h0b[i] = bb;
            if (i < 64*512) h0buf[i] = bb; else h1buf[i - 64*512] = bb;
          } break;
  case 2: for (long i = i0; i < 2048L*512; i += stride) W0[i] = (bf16_t)ldin(Wih0, i, mf); break;
  case 3: for (long i = i0; i < 2048L*512; i += stride) W1[i] = (bf16_t)ldin(Whh0, i, mf); break;
  case 4: for (long i = i0; i < 2048L*512; i += stride) W2[i] = (bf16_t)ldin(Wih1, i, mf); break;
  case 5: for (long i = i0; i < 2048L*512; i += stride) W3[i] = (bf16_t)ldin(Whh1, i, mf); break;
  case 6: for (long i = i0; i < 480L*512; i += stride){
            long r = i >> 9;
            Wifp[i] = (r < IFACE_) ? (bf16_t)ldin(Wif, i, mf) : (bf16_t)0.0f;
          } break;
  case 7: for (long i = i0; i < 256L*768; i += stride) Woutb[i] = (bf16_t)ldin(Wout, i, mf); break;
  case 8:
    for (long i = i0; i < 2048; i += stride){
      bs0[i] = ldin(bih0, i, mf) + ldin(bhh0, i, mf);
      bs1[i] = ldin(bih1, i, mf) + ldin(bhh1, i, mf);
    }
    for (long i = i0; i < 480; i += stride) bifp[i] = (i < IFACE_) ? ldin(bif, i, mf) : 0.0f;
    for (long i = i0; i < 256; i += stride) boutf[i] = ldin(bout, i, mf);
    break;
  }
}

// ---------------------------------------------------------------------------
// Persistent LSTM.  blocks 0..31: layer0 (units bid*16..+16); 32..63: layer1.
// Weights staged into LDS once (padded strides 264/520: 2-way bank = free).
__global__ __launch_bounds__(256,1) void k_lstm(
    const bf16_t* __restrict__ xb, const bf16_t* __restrict__ h0b,
    const bf16_t* __restrict__ W0, const bf16_t* __restrict__ W1,
    const bf16_t* __restrict__ W2, const bf16_t* __restrict__ W3,
    const float* __restrict__ bs0, const float* __restrict__ bs1,
    bf16_t* __restrict__ h0buf, bf16_t* __restrict__ h1buf,
    bf16_t* __restrict__ h0seq, bf16_t* __restrict__ outseq,
    unsigned* __restrict__ bar)
{
  __shared__ bf16_t wpool[66560];   // 133 KB weight pool
  __shared__ float cst[64][16];     // c-state [batch][unit-local]
  __shared__ float bias[4][16];

  const int bid = blockIdx.x;
  const int layer = bid >> 5;
  const int u0 = (bid & 31) * 16;
  const int tid = threadIdx.x;
  const int lane = tid & 63;
  const int wv = tid >> 6;          // 4 waves
  const int m16 = lane & 15, q = lane >> 4;

  // ---- stage weights into LDS (once) ----
  if (!layer){
    // Wx: 64 rows x 256 cols, stride 264, base 0
    for (int i = tid; i < 64*32; i += 256){
      int rl = i >> 5, c8 = (i & 31)*8;
      int grow = (rl >> 4)*512 + u0 + (rl & 15);
      *(bf16x8*)&wpool[rl*264 + c8] = *(const bf16x8*)(W0 + (size_t)grow*512 + c8);
    }
    // Wh: 64 x 512, stride 520, base 16896
    for (int i = tid; i < 64*64; i += 256){
      int rl = i >> 6, c8 = (i & 63)*8;
      int grow = (rl >> 4)*512 + u0 + (rl & 15);
      *(bf16x8*)&wpool[16896 + rl*520 + c8] = *(const bf16x8*)(W1 + (size_t)grow*512 + c8);
    }
  } else {
    for (int i = tid; i < 64*64; i += 256){
      int rl = i >> 6, c8 = (i & 63)*8;
      int grow = (rl >> 4)*512 + u0 + (rl & 15);
      *(bf16x8*)&wpool[rl*520 + c8]         = *(const bf16x8*)(W2 + (size_t)grow*512 + c8);
      *(bf16x8*)&wpool[33280 + rl*520 + c8] = *(const bf16x8*)(W3 + (size_t)grow*512 + c8);
    }
  }
  for (int i = tid; i < 64*16; i += 256){
    int b = i >> 4, n = i & 15;
    cst[b][n] = (float)h0b[layer*(64*512) + b*512 + u0 + n];  // c init = h init
  }
  if (tid < 64){
    int G = tid >> 4, n = tid & 15;
    const float* bs = layer ? bs1 : bs0;
    bias[G][n] = bs[G*512 + u0 + n];
  }
  __syncthreads();

  bf16_t* hbuf = layer ? h1buf : h0buf;

  for (int ps = 0; ps <= 32; ++ps){
    const int t = layer ? (ps - 1) : ps;
    const bool active = layer ? (ps >= 1) : (ps < 32);
    if (active){
      const int p = t & 1;
      const bf16_t* hin = hbuf + p*(64*512);
      bf16_t* hout = hbuf + (p^1)*(64*512);
      const int b0 = wv * 16;

      f32x4 acc[4];
      #pragma unroll
      for (int G = 0; G < 4; ++G){ float bv = bias[G][m16]; acc[G] = (f32x4){bv,bv,bv,bv}; }

      if (!layer){
        #pragma unroll 2
        for (int kt = 0; kt < 8; ++kt){
          bf16x8 a = *(const bf16x8*)(xb + ((size_t)(b0+m16)*T_ + t)*IN_ + kt*32 + q*8);
          #pragma unroll
          for (int G = 0; G < 4; ++G)
            acc[G] = __builtin_amdgcn_mfma_f32_16x16x32_bf16(
                a, *(const bf16x8*)&wpool[(G*16+m16)*264 + kt*32 + q*8], acc[G], 0, 0, 0);
        }
        #pragma unroll 4
        for (int kt = 0; kt < 16; ++kt){
          bf16x8 a = *(const bf16x8*)(hin + (b0+m16)*512 + kt*32 + q*8);
          #pragma unroll
          for (int G = 0; G < 4; ++G)
            acc[G] = __builtin_amdgcn_mfma_f32_16x16x32_bf16(
                a, *(const bf16x8*)&wpool[16896 + (G*16+m16)*520 + kt*32 + q*8], acc[G], 0, 0, 0);
        }
      } else {
        #pragma unroll 4
        for (int kt = 0; kt < 16; ++kt){
          bf16x8 a = *(const bf16x8*)(h0seq + ((size_t)t*64 + b0+m16)*512 + kt*32 + q*8);
          #pragma unroll
          for (int G = 0; G < 4; ++G)
            acc[G] = __builtin_amdgcn_mfma_f32_16x16x32_bf16(
                a, *(const bf16x8*)&wpool[(G*16+m16)*520 + kt*32 + q*8], acc[G], 0, 0, 0);
        }
        #pragma unroll 4
        for (int kt = 0; kt < 16; ++kt){
          bf16x8 a = *(const bf16x8*)(hin + (b0+m16)*512 + kt*32 + q*8);
          #pragma unroll
          for (int G = 0; G < 4; ++G)
            acc[G] = __builtin_amdgcn_mfma_f32_16x16x32_bf16(
                a, *(const bf16x8*)&wpool[33280 + (G*16+m16)*520 + kt*32 + q*8], acc[G], 0, 0, 0);
        }
      }
      #pragma unroll
      for (int v = 0; v < 4; ++v){
        int b = b0 + q*4 + v;
        float gi = acc[0][v], gf = acc[1][v], gg = acc[2][v], go = acc[3][v];
        float c_ = sigf(gf)*cst[b][m16] + sigf(gi)*tanhf(gg);
        cst[b][m16] = c_;
        float h = sigf(go)*tanhf(c_);
        bf16_t hb = (bf16_t)h;
        hout[b*512 + u0 + m16] = hb;
        if (!layer) h0seq[((size_t)t*64 + b)*512 + u0 + m16] = hb;
        else        outseq[((size_t)t*64 + b)*512 + u0 + m16] = hb;
      }
    }
    gridbar(bar, bar + 1, gridDim.x);
  }
}

// ---------------------------------------------------------------------------
__global__ __launch_bounds__(256,1) void k_xi(
    const bf16_t* __restrict__ outseq, const bf16_t* __restrict__ Wifp,
    const float* __restrict__ bifp, float* __restrict__ XI)
{
  const int mt = blockIdx.x;            // 0..127
  const int tid = threadIdx.x, lane = tid & 63, wv = tid >> 6;
  const int nt = blockIdx.y*4 + wv;     // 0..31
  if (nt >= 30) return;
  const int m16 = lane & 15, q = lane >> 4;
  const int r = nt*16 + m16;
  float bv = bifp[r];
  f32x4 acc = {bv,bv,bv,bv};
  const bf16_t* arow = outseq + (size_t)(mt*16 + m16)*512 + q*8;
  const bf16_t* brow = Wifp + (size_t)r*512 + q*8;
  for (int kt = 0; kt < 16; ++kt){
    bf16x8 a = *(const bf16x8*)(arow + kt*32);
    bf16x8 bb = *(const bf16x8*)(brow + kt*32);
    acc = __builtin_amdgcn_mfma_f32_16x16x32_bf16(a, bb, acc, 0, 0, 0);
  }
  #pragma unroll
  for (int v = 0; v < 4; ++v){
    int row = mt*16 + q*4 + v;
    XI[(size_t)row*480 + nt*16 + m16] = acc[v];
  }
}

// ---------------------------------------------------------------------------
__device__ __forceinline__ void softmax256_wave(float* a, int lane){
  float v0=a[lane], v1=a[64+lane], v2=a[128+lane], v3=a[192+lane];
  float mx = fmaxf(fmaxf(v0,v1), fmaxf(v2,v3));
  #pragma unroll
  for (int off=32; off; off>>=1) mx = fmaxf(mx, __shfl_xor(mx, off, 64));
  v0=expf(v0-mx); v1=expf(v1-mx); v2=expf(v2-mx); v3=expf(v3-mx);
  float s = v0+v1+v2+v3;
  #pragma unroll
  for (int off=32; off; off>>=1) s += __shfl_xor(s, off, 64);
  float inv = 1.0f/s;
  a[lane]=v0*inv; a[64+lane]=v1*inv; a[128+lane]=v2*inv; a[192+lane]=v3*inv;
}

// one block per batch; 512 threads = 8 waves (2/SIMD -> 256 VGPR budget so the
// link tiles stay in registers).  Wave wv owns link rows wv*32..+32 (two MFMA
// row-groups) in rowL (A-frag) and link cols wv*32..+32 in colL (B-frag).
__global__ __launch_bounds__(512,2) void k_mem(
    const float* __restrict__ XI, float* __restrict__ RVEC)
{
  const int b = blockIdx.x;
  const int tid = threadIdx.x, lane = tid & 63, wv = tid >> 6;   // wv 0..7
  const int quad = lane >> 4, li = lane & 15;

  __shared__ float smem[256][65];      // memory matrix
  __shared__ float xib[2][480];        // double-buffered interface vector
  __shared__ float rkn4r[2][65][4];    // [half][w][r] replicated
  __shared__ float wkn[64], ev_[64], wvv[64];
  __shared__ float rs_[4], fg_[4], rm_[4][3];
  __shared__ float wsS, agS, wgS, wwsumS;
  __shared__ float invn[256], wcw[256];
  __shared__ float usage[256], uu[256], su[256], scanA[256];
  __shared__ int   rank_[256];
  __shared__ float ww_[256], prec_[256];
  __shared__ float rw_[4][256];
  __shared__ float rw4[256][4];
  __shared__ float fwd_[4][256], bwd_[4][256], rcw_[4][256];
  __shared__ bf16_t rwb[4][264];
  __shared__ bf16_t wwb[256], precb[256];
  __shared__ float p2cT[2][264];       // [half][m]
  __shared__ float p5cT[5][2][264];    // [k][half][m]
  __shared__ float rvp[8][4][64];

  bf16x8 rowL[2][8], colL[2][8];
  #pragma unroll
  for (int g = 0; g < 2; ++g)
    #pragma unroll
    for (int ch = 0; ch < 8; ++ch)
      #pragma unroll
      for (int z = 0; z < 8; ++z){ rowL[g][ch][z] = (bf16_t)0.0f; colL[g][ch][z] = (bf16_t)0.0f; }

  // ---- init state ----
  if (tid < 256){
    ww_[tid] = DELTA_; usage[tid] = 0.0f; prec_[tid] = 0.0f;
    invn[tid] = 1.0f/(sqrtf(64.0f*DELTA_*DELTA_) + DELTA_);
    wwb[tid] = (bf16_t)DELTA_; precb[tid] = (bf16_t)0.0f;
    #pragma unroll
    for (int r = 0; r < 4; ++r) rw_[r][tid] = DELTA_;
  }
  for (int i = tid; i < 4*264; i += 512) ((bf16_t*)rwb)[i] = (bf16_t)DELTA_;
  for (int i = tid; i < 256*65; i += 512) ((float*)smem)[i] = DELTA_;
  if (tid < IFACE_) xib[0][tid] = XI[(size_t)b*480 + tid];
  __syncthreads();

  const int mH = tid >> 1, q2 = tid & 1;   // (row, half) split for row-par phases

  for (int t = 0; t < 32; ++t){
    const int tb = t & 1;
    // ---- R2: parse interface vector ----
    if (wv < 4){                                  // read keys: tanh + normalize
      float v = tanhf(xib[tb][wv*64 + lane]);
      float s = wred(v*v);
      float vn = v/(sqrtf(s) + DELTA_);
      rkn4r[0][lane][wv] = vn; rkn4r[1][lane][wv] = vn;
    } else if (wv == 4){                          // write key
      float v = tanhf(xib[tb][260 + lane]);
      float s = wred(v*v);
      wkn[lane] = v/(sqrtf(s) + DELTA_);
    } else if (wv == 5){ ev_[lane] = sigf(xib[tb][325 + lane]);
    } else if (wv == 6){ wvv[lane] = tanhf(xib[tb][389 + lane]);
    } else {
      if (lane < 4)        rs_[lane] = softplusf(xib[tb][256 + lane]);
      else if (lane == 4)  wsS = softplusf(xib[tb][324]);
      else if (lane < 9)   fg_[lane-5] = sigf(xib[tb][453 + (lane-5)]);
      else if (lane == 9)  agS = sigf(xib[tb][457]);
      else if (lane == 10) wgS = sigf(xib[tb][458]);
      else if (lane >= 16 && lane < 20){
        int r = lane - 16;
        float a0 = xib[tb][459+r*3], a1 = xib[tb][459+r*3+1], a2 = xib[tb][459+r*3+2];
        float mx = fmaxf(a0, fmaxf(a1, a2));
        float e0 = expf(a0-mx), e1 = expf(a1-mx), e2 = expf(a2-mx);
        float s = e0+e1+e2;
        rm_[r][0]=e0/s; rm_[r][1]=e1/s; rm_[r][2]=e2/s;
      }
    }
    __syncthreads();

    // ---- R3: usage update (tid<256) + write-content partials (all) ----
    if (tid < 256){
      int m = tid;
      float us = usage[m] + (1.0f - usage[m])*ww_[m];
      float psi = (1.0f - fg_[0]*rw_[0][m]) * (1.0f - fg_[1]*rw_[1][m])
                * (1.0f - fg_[2]*rw_[2][m]) * (1.0f - fg_[3]*rw_[3][m]);
      us *= psi;
      usage[m] = us;
      uu[m] = DELTA_ + (1.0f - DELTA_)*us;
    }
    { float acc = 0.0f;
      #pragma unroll
      for (int it = 0; it < 32; ++it){
        int w = q2*32 + it;
        acc += smem[mH][w] * wkn[w];
      }
      p2cT[q2][mH] = acc; }
    __syncthreads();

    // ---- R4: wave0: wcw combine + softmax ; waves 4-7: full rank-sort ----
    if (wv == 0){
      #pragma unroll
      for (int z = 0; z < 4; ++z){
        int m = z*64 + lane;
        wcw[m] = wsS * (p2cT[0][m] + p2cT[1][m]) * invn[m];
      }
      softmax256_wave(wcw, lane);
    } else if (tid >= 256){
      const int i = tid - 256;
      const float ui = uu[i];
      int cnt = 0;
      #pragma unroll 8
      for (int k = 0; k < 64; ++k){
        f32x4 u4 = *(const f32x4*)&uu[k*4];
        #pragma unroll
        for (int z = 0; z < 4; ++z){
          int j = k*4 + z; float uj = u4[z];
          cnt += (uj < ui || (uj == ui && j < i)) ? 1 : 0;
        }
      }
      rank_[i] = cnt;
      su[cnt] = ui;
    }
    __syncthreads();

    // ---- R5: exclusive product scan of su -> scanA (wave 0) ----
    if (wv == 0){
      int base = lane*4;
      float v0 = su[base], v1 = su[base+1], v2 = su[base+2];
      float p1 = v0*v1, p2 = p1*v2, p3 = p2*su[base+3];
      float sc = p3;
      #pragma unroll
      for (int off = 1; off < 64; off <<= 1){
        float n = __shfl_up(sc, off, 64);
        if (lane >= off) sc *= n;
      }
      float exch = __shfl_up(sc, 1, 64);
      if (lane == 0) exch = 1.0f;
      scanA[base] = exch; scanA[base+1] = exch*v0;
      scanA[base+2] = exch*p1; scanA[base+3] = exch*p2;
    }
    __syncthreads();

    // ---- R7: ww (redundant per half) + mem erase/write + partials ----
    { const int m = mH;
      float al = (1.0f - uu[m]) * scanA[rank_[m]];
      float wm = wgS*(agS*al + (1.0f - agS)*wcw[m]);
      if (q2 == 0){ ww_[m] = wm; wwb[m] = (bf16_t)wm; }
      float s2 = 0.0f, sr0 = 0.0f, sr1 = 0.0f, sr2 = 0.0f, sr3 = 0.0f;
      #pragma unroll
      for (int it = 0; it < 32; ++it){
        int w = q2*32 + it;
        float mn = smem[m][w]*(1.0f - wm*ev_[w]) + wm*wvv[w];
        smem[m][w] = mn;
        s2 += mn*mn;
        f32x4 rk = *(const f32x4*)&rkn4r[q2][w][0];
        sr0 += mn*rk[0]; sr1 += mn*rk[1]; sr2 += mn*rk[2]; sr3 += mn*rk[3];
      }
      p5cT[0][q2][m] = s2;
      p5cT[1][q2][m] = sr0; p5cT[2][q2][m] = sr1;
      p5cT[3][q2][m] = sr2; p5cT[4][q2][m] = sr3; }
    __syncthreads();

    // ---- R8: norm + read-content pre-softmax (tid<256); wave4: wwsum ----
    if (tid < 256){
      int m = tid;
      float s2 = p5cT[0][0][m] + p5cT[0][1][m];
      float inv = 1.0f/(sqrtf(s2) + DELTA_);
      invn[m] = inv;
      #pragma unroll
      for (int r = 0; r < 4; ++r){
        float sr = p5cT[r+1][0][m] + p5cT[r+1][1][m];
        rcw_[r][m] = rs_[r]*sr*inv;
      }
    } else if (wv == 4){
      float s = wred(ww_[lane] + ww_[64+lane] + ww_[128+lane] + ww_[192+lane]);
      if (lane == 0) wwsumS = s;
    }
    __syncthreads();

    // ---- R9: link update + fwd/bwd via MFMA (all 8 waves, 2 row-groups) ----
    { float wown[2], pown[2];
      #pragma unroll
      for (int g = 0; g < 2; ++g){
        int o = wv*32 + g*16 + li;
        wown[g] = (float)wwb[o]; pown[g] = (float)precb[o];
      }
      f32x4 facc[2] = {{0,0,0,0},{0,0,0,0}}, bacc[2] = {{0,0,0,0},{0,0,0,0}};
      #pragma unroll
      for (int ch = 0; ch < 8; ++ch){
        const int cbase = ch*32 + quad*8;
        bf16x8 rwf = *(const bf16x8*)&rwb[li & 3][cbase];
        bf16x8 wwv = *(const bf16x8*)&wwb[cbase];
        bf16x8 pcv = *(const bf16x8*)&precb[cbase];
        #pragma unroll
        for (int g = 0; g < 2; ++g){
          const int o = wv*32 + g*16 + li;
          bf16x8 rl = rowL[g][ch];
          bf16x8 cl = colL[g][ch];
          #pragma unroll
          for (int jj = 0; jj < 8; ++jj){
            const int c = cbase + jj;
            float wc = (float)wwv[jj];
            float pc = (float)pcv[jj];
            float vr = (1.0f - wown[g] - wc)*(float)rl[jj] + wown[g]*pc;
            float vc = (1.0f - wc - wown[g])*(float)cl[jj] + wc*pown[g];
            if (c == o){ vr = 0.0f; vc = 0.0f; }
            rl[jj] = (bf16_t)vr;
            cl[jj] = (bf16_t)vc;
          }
          rowL[g][ch] = rl; colL[g][ch] = cl;
          facc[g] = __builtin_amdgcn_mfma_f32_16x16x32_bf16(rl, rwf, facc[g], 0, 0, 0);
          bacc[g] = __builtin_amdgcn_mfma_f32_16x16x32_bf16(rwf, cl, bacc[g], 0, 0, 0);
        }
      }
      #pragma unroll
      for (int g = 0; g < 2; ++g){
        if (li < 4){
          #pragma unroll
          for (int z = 0; z < 4; ++z) fwd_[li][wv*32 + g*16 + quad*4 + z] = facc[g][z];
        }
        if (quad == 0){
          #pragma unroll
          for (int z = 0; z < 4; ++z) bwd_[z][wv*32 + g*16 + li] = bacc[g][z];
        }
      }
    }
    __syncthreads();

    // ---- R10: waves0-3: rcw softmax ; waves4-7: precedence ----
    if (wv < 4) softmax256_wave(rcw_[wv], lane);
    else if (tid < 512){
      int m = tid - 256;
      float p = (1.0f - wwsumS)*prec_[m] + ww_[m];
      prec_[m] = p;
      precb[m] = (bf16_t)p;
    }
    __syncthreads();

    // ---- R11: new read weights (512 threads x 2 slots) ----
    { int r = tid >> 7, m0 = (tid & 127)*2;
      #pragma unroll
      for (int z = 0; z < 2; ++z){
        int m = m0 + z;
        float v = rm_[r][0]*bwd_[r][m] + rm_[r][1]*fwd_[r][m] + rm_[r][2]*rcw_[r][m];
        rw_[r][m] = v;
        rw4[m][r] = v;
        rwb[r][m] = (bf16_t)v;
      } }
    __syncthreads();

    // ---- R12: read vectors: wave-per-32-rows ----
    { float r0 = 0, r1 = 0, r2 = 0, r3 = 0;
      #pragma unroll
      for (int k = 0; k < 32; ++k){
        int m = wv*32 + k;
        f32x4 r4 = *(const f32x4*)&rw4[m][0];
        float mv = smem[m][lane];
        r0 += r4[0]*mv; r1 += r4[1]*mv; r2 += r4[2]*mv; r3 += r4[3]*mv;
      }
      rvp[wv][0][lane] = r0; rvp[wv][1][lane] = r1;
      rvp[wv][2][lane] = r2; rvp[wv][3][lane] = r3; }
    __syncthreads();

    // ---- R13: combine + store; idle threads prefetch next xi ----
    if (tid < 256){
      const int w = tid & 63, r = tid >> 6;
      float v = 0.0f;
      #pragma unroll
      for (int c = 0; c < 8; ++c) v += rvp[c][r][w];
      RVEC[((size_t)t*64 + b)*256 + tid] = v;
    } else if (t + 1 < 32){
      int j = tid - 256;
      const float* xn = XI + ((size_t)(t+1)*64 + b)*480;
      xib[(t+1)&1][j] = xn[j];
      if (j + 256 < IFACE_) xib[(t+1)&1][j+256] = xn[j+256];
    }
    __syncthreads();
  }
}

// ---------------------------------------------------------------------------
__global__ void k_tanhy(const bf16_t* __restrict__ outseq, const float* __restrict__ RVEC,
                        bf16_t* __restrict__ Y){
  const int n = 2048*768;
  for (int i = blockIdx.x*blockDim.x + threadIdx.x; i < n; i += gridDim.x*blockDim.x){
    int row = i / 768, j = i - row*768;
    float v = (j < 512) ? (float)outseq[(size_t)row*512 + j] : RVEC[(size_t)row*256 + (j - 512)];
    Y[i] = (bf16_t)tanhf(v);
  }
}

__global__ __launch_bounds__(256,1) void k_out(
    const bf16_t* __restrict__ Y, const bf16_t* __restrict__ Woutb,
    const float* __restrict__ boutf, void* __restrict__ dout,
    const int* __restrict__ flag)
{
  const int mf = *flag;
  const int mt = blockIdx.x;          // 0..127
  const int tid = threadIdx.x, lane = tid & 63, wv = tid >> 6;
  const int nt = blockIdx.y*4 + wv;   // 0..15
  const int m16 = lane & 15, q = lane >> 4;
  const int o = nt*16 + m16;
  float bv = boutf[o];
  f32x4 acc = {bv,bv,bv,bv};
  const bf16_t* arow = Y + (size_t)(mt*16 + m16)*768 + q*8;
  const bf16_t* brow = Woutb + (size_t)o*768 + q*8;
  for (int kt = 0; kt < 24; ++kt){
    acc = __builtin_amdgcn_mfma_f32_16x16x32_bf16(
        *(const bf16x8*)(arow + kt*32), *(const bf16x8*)(brow + kt*32), acc, 0, 0, 0);
  }
  #pragma unroll
  for (int v = 0; v < 4; ++v){
    int row = mt*16 + q*4 + v;        // = t*64 + b
    int b = row & 63, t = row >> 6;
    size_t idx = ((size_t)b*T_ + t)*256 + o;
    if (mf) ((float*)dout)[idx] = acc[v];
    else    ((bf16_t*)dout)[idx] = (bf16_t)acc[v];
  }
}

// ---------------------------------------------------------------------------
extern "C" void kernel_launch(void* const* d_in, const int* in_sizes, int n_in,
                              void* d_out, int out_size, void* d_ws, size_t ws_size,
                              hipStream_t stream)
{
  char* ws = (char*)d_ws;
  bf16_t* H0SEQ  = (bf16_t*)(ws + OFF_H0SEQ);
  bf16_t* OUTSEQ = (bf16_t*)(ws + OFF_OUTSEQ);
  bf16_t* H0BUF  = (bf16_t*)(ws + OFF_H0BUF);
  bf16_t* H1BUF  = (bf16_t*)(ws + OFF_H1BUF);
  float*  XI     = (float*) (ws + OFF_XI);
  float*  RVEC   = (float*) (ws + OFF_RVEC);
  bf16_t* YBF    = (bf16_t*)(ws + OFF_YBF);
  unsigned* BAR  = (unsigned*)(ws + OFF_BAR);
  int*    FLAG   = (int*)   (ws + OFF_BAR + 8);
  bf16_t* XB     = (bf16_t*)(ws + OFF_XB);
  bf16_t* H0B    = (bf16_t*)(ws + OFF_H0B);
  bf16_t* W0     = (bf16_t*)(ws + OFF_W0);
  bf16_t* W1     = (bf16_t*)(ws + OFF_W1);
  bf16_t* W2     = (bf16_t*)(ws + OFF_W2);
  bf16_t* W3     = (bf16_t*)(ws + OFF_W3);
  bf16_t* WIFP   = (bf16_t*)(ws + OFF_WIF);
  bf16_t* WOUTB  = (bf16_t*)(ws + OFF_WOUTB);
  float*  BS0    = (float*) (ws + OFF_BS0);
  float*  BS1    = (float*) (ws + OFF_BS1);
  float*  BIFP   = (float*) (ws + OFF_BIF);
  float*  BOUTF  = (float*) (ws + OFF_BOUTF);

  k_detect<<<1, 256, 0, stream>>>((const unsigned short*)d_in[0], FLAG, BAR);
  k_convert<<<dim3(256, 9), 256, 0, stream>>>(
      d_in[0], d_in[1], d_in[2], d_in[3], d_in[4], d_in[5], d_in[6],
      d_in[7], d_in[8], d_in[9], d_in[10], d_in[11], d_in[12], d_in[13],
      XB, H0B, H0BUF, H1BUF, W0, W1, W2, W3, WIFP, WOUTB,
      BS0, BS1, BIFP, BOUTF, FLAG);
  k_lstm<<<64, 256, 0, stream>>>(XB, H0B, W0, W1, W2, W3, BS0, BS1,
                                 H0BUF, H1BUF, H0SEQ, OUTSEQ, BAR);
  k_xi<<<dim3(128, 8), 256, 0, stream>>>(OUTSEQ, WIFP, BIFP, XI);
  k_mem<<<64, 512, 0, stream>>>(XI, RVEC);
  k_tanhy<<<512, 256, 0, stream>>>(OUTSEQ, RVEC, YBF);
  k_out<<<dim3(128, 4), 256, 0, stream>>>(YBF, WOUTB, BOUTF, d_out, FLAG);
}

// Round 8
// 1140.867 us; speedup vs baseline: 3.4518x; 1.0881x over previous
//
#include <hip/hip_runtime.h>
#include <hip/hip_bf16.h>
#include <math.h>

// ---------------------------------------------------------------------------
// DNC forward on MI355X.
//   k_detect  : device-side input-dtype detection (f32 vs bf16) + bar zero
//   k_convert : canonicalize all inputs -> internal bf16/f32 buffers
//   k_main    : FUSED producer/consumer kernel, 128 blocks x 512 threads:
//               blocks 0-63  = persistent LSTM (waves 0-3) + xi GEMM tiles
//                              (waves 4-7, for t-2), 34 producer grid barriers
//               blocks 64-127= memory recurrence (1 block/batch), gated on the
//                              producer barrier generation (XI[t] @ gen>=t+3);
//                              link in MFMA-layout registers, fwd/bwd via MFMA
//   k_tanhy   : tanh([out, rvec]) -> bf16
//   k_out     : output GEMM (2048 x 256 x 768) MFMA -> d_out (dtype per flag)
// ---------------------------------------------------------------------------

typedef __bf16 bf16_t;
typedef __attribute__((ext_vector_type(8))) __bf16 bf16x8;
typedef __attribute__((ext_vector_type(4))) float f32x4;

#define B_    64
#define T_    32
#define IN_   256
#define H_    512
#define M_    256
#define W_    64
#define R_    4
#define IFACE_ 471
#define DELTA_ 1e-6f

// ---------------- ws layout (bytes) ----------------
#define OFF_H0SEQ  (0L)
#define SZ_H0SEQ   (32L*64*512*2)
#define OFF_OUTSEQ (OFF_H0SEQ + SZ_H0SEQ)
#define SZ_OUTSEQ  (32L*64*512*2)
#define OFF_H0BUF  (OFF_OUTSEQ + SZ_OUTSEQ)
#define SZ_HBUF    (2L*64*512*2)
#define OFF_H1BUF  (OFF_H0BUF + SZ_HBUF)
#define OFF_XI     (OFF_H1BUF + SZ_HBUF)
#define SZ_XI      (32L*64*480*4)
#define OFF_RVEC   (OFF_XI + SZ_XI)
#define SZ_RVEC    (32L*64*256*4)
#define OFF_YBF    (OFF_RVEC + SZ_RVEC)
#define SZ_YBF     (32L*64*768*2)
#define OFF_BAR    (OFF_YBF + SZ_YBF)
#define SZ_BAR     (256L)                 // bar[2] + flag
#define OFF_XB     (OFF_BAR + SZ_BAR)
#define SZ_XB      (64L*32*256*2)
#define OFF_H0B    (OFF_XB + SZ_XB)
#define SZ_H0B     (2L*64*512*2)
#define OFF_W0     (OFF_H0B + SZ_H0B)
#define SZ_W       (2048L*512*2)
#define OFF_W1     (OFF_W0 + SZ_W)
#define OFF_W2     (OFF_W1 + SZ_W)
#define OFF_W3     (OFF_W2 + SZ_W)
#define OFF_WIF    (OFF_W3 + SZ_W)
#define SZ_WIF     (480L*512*2)
#define OFF_WOUTB  (OFF_WIF + SZ_WIF)
#define SZ_WOUTB   (256L*768*2)
#define OFF_BS0    (OFF_WOUTB + SZ_WOUTB)
#define SZ_BS      (2048L*4)
#define OFF_BS1    (OFF_BS0 + SZ_BS)
#define OFF_BIF    (OFF_BS1 + SZ_BS)
#define SZ_BIF     (2048L)
#define OFF_BOUTF  (OFF_BIF + SZ_BIF)
#define SZ_BOUTF   (1024L)

__device__ __forceinline__ float sigf(float x){ return 1.0f/(1.0f + expf(-x)); }
__device__ __forceinline__ float softplusf(float x){
  return fmaxf(x, 0.0f) + log1pf(expf(-fabsf(x)));
}
__device__ __forceinline__ float wred(float v){
  #pragma unroll
  for (int off = 32; off; off >>= 1) v += __shfl_xor(v, off, 64);
  return v;
}
__device__ __forceinline__ float ldin(const void* p, long i, int mf){
  return mf ? ((const float*)p)[i] : (float)((const bf16_t*)p)[i];
}

// agent-scope generation barrier over nb blocks (producer blocks only)
__device__ __forceinline__ void gridbar(unsigned* cnt, unsigned* gen, unsigned nb){
  __syncthreads();
  if (threadIdx.x == 0){
    unsigned g = __hip_atomic_load(gen, __ATOMIC_ACQUIRE, __HIP_MEMORY_SCOPE_AGENT);
    unsigned a = __hip_atomic_fetch_add(cnt, 1u, __ATOMIC_ACQ_REL, __HIP_MEMORY_SCOPE_AGENT);
    if (a == nb - 1u){
      __hip_atomic_store(cnt, 0u, __ATOMIC_RELAXED, __HIP_MEMORY_SCOPE_AGENT);
      __hip_atomic_fetch_add(gen, 1u, __ATOMIC_ACQ_REL, __HIP_MEMORY_SCOPE_AGENT);
    } else {
      while (__hip_atomic_load(gen, __ATOMIC_ACQUIRE, __HIP_MEMORY_SCOPE_AGENT) == g)
        __builtin_amdgcn_s_sleep(2);
    }
  }
  __syncthreads();
}

// ---------------------------------------------------------------------------
__global__ void k_detect(const unsigned short* __restrict__ x16,
                         int* __restrict__ flag, unsigned* __restrict__ bar){
  __shared__ int cnt;
  if (threadIdx.x == 0){ cnt = 0; bar[0] = 0u; bar[1] = 0u; }
  __syncthreads();
  unsigned short u = x16[threadIdx.x * 2];
  int e = (u >> 7) & 0xFF;
  if (e >= 0x88) atomicAdd(&cnt, 1);
  __syncthreads();
  if (threadIdx.x == 0) *flag = (cnt > 16) ? 1 : 0;
}

// ---------------------------------------------------------------------------
__global__ void k_convert(const void* x, const void* h0, const void* Wih0,
                          const void* Whh0, const void* bih0, const void* bhh0,
                          const void* Wih1, const void* Whh1, const void* bih1,
                          const void* bhh1, const void* Wif, const void* bif,
                          const void* Wout, const void* bout,
                          bf16_t* __restrict__ xb, bf16_t* __restrict__ h0b,
                          bf16_t* __restrict__ h0buf, bf16_t* __restrict__ h1buf,
                          bf16_t* __restrict__ W0, bf16_t* __restrict__ W1,
                          bf16_t* __restrict__ W2, bf16_t* __restrict__ W3,
                          bf16_t* __restrict__ Wifp, bf16_t* __restrict__ Woutb,
                          float* __restrict__ bs0, float* __restrict__ bs1,
                          float* __restrict__ bifp, float* __restrict__ boutf,
                          const int* __restrict__ flag)
{
  const int mf = *flag;
  const long stride = (long)gridDim.x * blockDim.x;
  long i0 = (long)blockIdx.x * blockDim.x + threadIdx.x;
  switch (blockIdx.y){
  case 0: for (long i = i0; i < 64L*32*256; i += stride) xb[i] = (bf16_t)ldin(x, i, mf); break;
  case 1: for (long i = i0; i < 2L*64*512; i += stride){
            float v = ldin(h0, i, mf); bf16_t bb = (bf16_t)v; h0b[i] = bb;
            if (i < 64*512) h0buf[i] = bb; else h1buf[i - 64*512] = bb;
          } break;
  case 2: for (long i = i0; i < 2048L*512; i += stride) W0[i] = (bf16_t)ldin(Wih0, i, mf); break;
  case 3: for (long i = i0; i < 2048L*512; i += stride) W1[i] = (bf16_t)ldin(Whh0, i, mf); break;
  case 4: for (long i = i0; i < 2048L*512; i += stride) W2[i] = (bf16_t)ldin(Wih1, i, mf); break;
  case 5: for (long i = i0; i < 2048L*512; i += stride) W3[i] = (bf16_t)ldin(Whh1, i, mf); break;
  case 6: for (long i = i0; i < 480L*512; i += stride){
            long r = i >> 9;
            Wifp[i] = (r < IFACE_) ? (bf16_t)ldin(Wif, i, mf) : (bf16_t)0.0f;
          } break;
  case 7: for (long i = i0; i < 256L*768; i += stride) Woutb[i] = (bf16_t)ldin(Wout, i, mf); break;
  case 8:
    for (long i = i0; i < 2048; i += stride){
      bs0[i] = ldin(bih0, i, mf) + ldin(bhh0, i, mf);
      bs1[i] = ldin(bih1, i, mf) + ldin(bhh1, i, mf);
    }
    for (long i = i0; i < 480; i += stride) bifp[i] = (i < IFACE_) ? ldin(bif, i, mf) : 0.0f;
    for (long i = i0; i < 256; i += stride) boutf[i] = ldin(bout, i, mf);
    break;
  }
}

// ---------------------------------------------------------------------------
__device__ __forceinline__ void softmax256_wave(float* a, int lane){
  float v0=a[lane], v1=a[64+lane], v2=a[128+lane], v3=a[192+lane];
  float mx = fmaxf(fmaxf(v0,v1), fmaxf(v2,v3));
  #pragma unroll
  for (int off=32; off; off>>=1) mx = fmaxf(mx, __shfl_xor(mx, off, 64));
  v0=expf(v0-mx); v1=expf(v1-mx); v2=expf(v2-mx); v3=expf(v3-mx);
  float s = v0+v1+v2+v3;
  #pragma unroll
  for (int off=32; off; off>>=1) s += __shfl_xor(s, off, 64);
  float inv = 1.0f/s;
  a[lane]=v0*inv; a[64+lane]=v1*inv; a[128+lane]=v2*inv; a[192+lane]=v3*inv;
}

// ---- LDS overlays -------------------------------------------------------
struct ProdShm {
  bf16_t wpool[66560];     // 133 KB weight pool
  float  cst[64][16];
  float  bias[4][16];
};
struct ConsShm {
  float smem[256][65];
  float xib[480];
  float rkn4r[2][65][4];
  float wkn[64], ev_[64], wvv[64];
  float rs_[4], fg_[4], rm_[4][3];
  float wsS, agS, wgS, wwsumS;
  float invn[256], wcw[256];
  float usage[256], uu[256], su[256], scanA[256];
  int   rank_[256];
  float ww_[256], prec_[256];
  float rw_[4][256];
  float rw4[256][4];
  float fwd_[4][256], bwd_[4][256], rcw_[4][256];
  bf16_t rwb[4][264];
  bf16_t wwb[256], precb[256];
  float p2cT[2][264];
  float p5cT[5][2][264];
  float rvp[8][4][64];
};
union ShUnion { ProdShm p; ConsShm c; };

// ---------------------------------------------------------------------------
// Fused producer/consumer kernel.  128 blocks x 512 threads.
__global__ __launch_bounds__(512,2) void k_main(
    const bf16_t* __restrict__ xb, const bf16_t* __restrict__ h0b,
    const bf16_t* __restrict__ W0, const bf16_t* __restrict__ W1,
    const bf16_t* __restrict__ W2, const bf16_t* __restrict__ W3,
    const float* __restrict__ bs0, const float* __restrict__ bs1,
    const bf16_t* __restrict__ Wifp, const float* __restrict__ bifp,
    bf16_t* __restrict__ h0buf, bf16_t* __restrict__ h1buf,
    bf16_t* __restrict__ h0seq, bf16_t* __restrict__ outseq,
    float* __restrict__ XI, float* __restrict__ RVEC,
    unsigned* __restrict__ bar)
{
  __shared__ ShUnion sh;
  const int bid = blockIdx.x;
  const int tid = threadIdx.x, lane = tid & 63, wv = tid >> 6;
  const int m16 = lane & 15, q = lane >> 4;

  if (bid < 64){
    // ===================== PRODUCER: LSTM + xi tiles ======================
    ProdShm& P = sh.p;
    const int layer = bid >> 5;
    const int u0 = (bid & 31) * 16;

    if (!layer){
      for (int i = tid; i < 64*32; i += 512){
        int rl = i >> 5, c8 = (i & 31)*8;
        int grow = (rl >> 4)*512 + u0 + (rl & 15);
        *(bf16x8*)&P.wpool[rl*264 + c8] = *(const bf16x8*)(W0 + (size_t)grow*512 + c8);
      }
      for (int i = tid; i < 64*64; i += 512){
        int rl = i >> 6, c8 = (i & 63)*8;
        int grow = (rl >> 4)*512 + u0 + (rl & 15);
        *(bf16x8*)&P.wpool[16896 + rl*520 + c8] = *(const bf16x8*)(W1 + (size_t)grow*512 + c8);
      }
    } else {
      for (int i = tid; i < 64*64; i += 512){
        int rl = i >> 6, c8 = (i & 63)*8;
        int grow = (rl >> 4)*512 + u0 + (rl & 15);
        *(bf16x8*)&P.wpool[rl*520 + c8]         = *(const bf16x8*)(W2 + (size_t)grow*512 + c8);
        *(bf16x8*)&P.wpool[33280 + rl*520 + c8] = *(const bf16x8*)(W3 + (size_t)grow*512 + c8);
      }
    }
    for (int i = tid; i < 64*16; i += 512){
      int b = i >> 4, n = i & 15;
      P.cst[b][n] = (float)h0b[layer*(64*512) + b*512 + u0 + n];
    }
    if (tid < 64){
      int G = tid >> 4, n = tid & 15;
      const float* bs = layer ? bs1 : bs0;
      P.bias[G][n] = bs[G*512 + u0 + n];
    }
    __syncthreads();

    bf16_t* hbuf = layer ? h1buf : h0buf;

    for (int ps = 0; ps <= 33; ++ps){
      if (wv < 4){
        const int t = layer ? (ps - 1) : ps;
        const bool active = layer ? (ps >= 1 && ps <= 32) : (ps < 32);
        if (active){
          const int p = t & 1;
          const bf16_t* hin = hbuf + p*(64*512);
          bf16_t* hout = hbuf + (p^1)*(64*512);
          const int b0 = wv * 16;

          f32x4 acc[4];
          #pragma unroll
          for (int G = 0; G < 4; ++G){ float bv = P.bias[G][m16]; acc[G] = (f32x4){bv,bv,bv,bv}; }

          if (!layer){
            #pragma unroll 2
            for (int kt = 0; kt < 8; ++kt){
              bf16x8 a = *(const bf16x8*)(xb + ((size_t)(b0+m16)*T_ + t)*IN_ + kt*32 + q*8);
              #pragma unroll
              for (int G = 0; G < 4; ++G)
                acc[G] = __builtin_amdgcn_mfma_f32_16x16x32_bf16(
                    a, *(const bf16x8*)&P.wpool[(G*16+m16)*264 + kt*32 + q*8], acc[G], 0, 0, 0);
            }
            #pragma unroll 4
            for (int kt = 0; kt < 16; ++kt){
              bf16x8 a = *(const bf16x8*)(hin + (b0+m16)*512 + kt*32 + q*8);
              #pragma unroll
              for (int G = 0; G < 4; ++G)
                acc[G] = __builtin_amdgcn_mfma_f32_16x16x32_bf16(
                    a, *(const bf16x8*)&P.wpool[16896 + (G*16+m16)*520 + kt*32 + q*8], acc[G], 0, 0, 0);
            }
          } else {
            #pragma unroll 4
            for (int kt = 0; kt < 16; ++kt){
              bf16x8 a = *(const bf16x8*)(h0seq + ((size_t)t*64 + b0+m16)*512 + kt*32 + q*8);
              #pragma unroll
              for (int G = 0; G < 4; ++G)
                acc[G] = __builtin_amdgcn_mfma_f32_16x16x32_bf16(
                    a, *(const bf16x8*)&P.wpool[(G*16+m16)*520 + kt*32 + q*8], acc[G], 0, 0, 0);
            }
            #pragma unroll 4
            for (int kt = 0; kt < 16; ++kt){
              bf16x8 a = *(const bf16x8*)(hin + (b0+m16)*512 + kt*32 + q*8);
              #pragma unroll
              for (int G = 0; G < 4; ++G)
                acc[G] = __builtin_amdgcn_mfma_f32_16x16x32_bf16(
                    a, *(const bf16x8*)&P.wpool[33280 + (G*16+m16)*520 + kt*32 + q*8], acc[G], 0, 0, 0);
            }
          }
          #pragma unroll
          for (int v = 0; v < 4; ++v){
            int b = b0 + q*4 + v;
            float gi = acc[0][v], gf = acc[1][v], gg = acc[2][v], go = acc[3][v];
            float c_ = sigf(gf)*P.cst[b][m16] + sigf(gi)*tanhf(gg);
            P.cst[b][m16] = c_;
            float h = sigf(go)*tanhf(c_);
            bf16_t hb = (bf16_t)h;
            hout[b*512 + u0 + m16] = hb;
            if (!layer) h0seq[((size_t)t*64 + b)*512 + u0 + m16] = hb;
            else        outseq[((size_t)t*64 + b)*512 + u0 + m16] = hb;
          }
        }
      } else if (ps >= 2 && bid < 30){
        // xi tile for t2 = ps-2: rows bid*16..+16, batch-tile per wave
        const int t2 = ps - 2;
        const int b0 = (wv - 4) * 16;
        const int r = bid*16 + m16;          // < 480 (rows 471..479 zero-padded)
        float bv = bifp[r];
        f32x4 acc = {bv,bv,bv,bv};
        const bf16_t* arow = outseq + ((size_t)t2*64 + b0 + m16)*512 + q*8;
        const bf16_t* brow = Wifp + (size_t)r*512 + q*8;
        #pragma unroll 4
        for (int kt = 0; kt < 16; ++kt){
          acc = __builtin_amdgcn_mfma_f32_16x16x32_bf16(
              *(const bf16x8*)(arow + kt*32), *(const bf16x8*)(brow + kt*32), acc, 0, 0, 0);
        }
        #pragma unroll
        for (int v = 0; v < 4; ++v)
          XI[((size_t)t2*64 + b0 + q*4 + v)*480 + r] = acc[v];
      }
      gridbar(bar, bar + 1, 64);
    }
  } else {
    // ===================== CONSUMER: memory recurrence ====================
    ConsShm& S = sh.c;
    const int b = bid - 64;
    const int quad = lane >> 4, li = lane & 15;

    bf16x8 rowL[2][8], colL[2][8];
    #pragma unroll
    for (int g = 0; g < 2; ++g)
      #pragma unroll
      for (int ch = 0; ch < 8; ++ch)
        #pragma unroll
        for (int z = 0; z < 8; ++z){ rowL[g][ch][z] = (bf16_t)0.0f; colL[g][ch][z] = (bf16_t)0.0f; }

    if (tid < 256){
      S.ww_[tid] = DELTA_; S.usage[tid] = 0.0f; S.prec_[tid] = 0.0f;
      S.invn[tid] = 1.0f/(sqrtf(64.0f*DELTA_*DELTA_) + DELTA_);
      S.wwb[tid] = (bf16_t)DELTA_; S.precb[tid] = (bf16_t)0.0f;
      #pragma unroll
      for (int r = 0; r < 4; ++r) S.rw_[r][tid] = DELTA_;
    }
    for (int i = tid; i < 4*264; i += 512) ((bf16_t*)S.rwb)[i] = (bf16_t)DELTA_;
    for (int i = tid; i < 256*65; i += 512) ((float*)S.smem)[i] = DELTA_;
    __syncthreads();

    const int mH = tid >> 1, q2 = tid & 1;

    for (int t = 0; t < 32; ++t){
      // ---- R1: wait for XI[t] (producer gen >= t+3), then load ----
      if (tid == 0){
        while (__hip_atomic_load(bar + 1, __ATOMIC_ACQUIRE, __HIP_MEMORY_SCOPE_AGENT)
               < (unsigned)(t + 3))
          __builtin_amdgcn_s_sleep(2);
      }
      __syncthreads();
      if (tid < IFACE_) S.xib[tid] = XI[((size_t)t*64 + b)*480 + tid];
      __syncthreads();

      // ---- R2: parse interface vector ----
      if (wv < 4){
        float v = tanhf(S.xib[wv*64 + lane]);
        float s = wred(v*v);
        float vn = v/(sqrtf(s) + DELTA_);
        S.rkn4r[0][lane][wv] = vn; S.rkn4r[1][lane][wv] = vn;
      } else if (wv == 4){
        float v = tanhf(S.xib[260 + lane]);
        float s = wred(v*v);
        S.wkn[lane] = v/(sqrtf(s) + DELTA_);
      } else if (wv == 5){ S.ev_[lane] = sigf(S.xib[325 + lane]);
      } else if (wv == 6){ S.wvv[lane] = tanhf(S.xib[389 + lane]);
      } else {
        if (lane < 4)        S.rs_[lane] = softplusf(S.xib[256 + lane]);
        else if (lane == 4)  S.wsS = softplusf(S.xib[324]);
        else if (lane < 9)   S.fg_[lane-5] = sigf(S.xib[453 + (lane-5)]);
        else if (lane == 9)  S.agS = sigf(S.xib[457]);
        else if (lane == 10) S.wgS = sigf(S.xib[458]);
        else if (lane >= 16 && lane < 20){
          int r = lane - 16;
          float a0 = S.xib[459+r*3], a1 = S.xib[459+r*3+1], a2 = S.xib[459+r*3+2];
          float mx = fmaxf(a0, fmaxf(a1, a2));
          float e0 = expf(a0-mx), e1 = expf(a1-mx), e2 = expf(a2-mx);
          float s = e0+e1+e2;
          S.rm_[r][0]=e0/s; S.rm_[r][1]=e1/s; S.rm_[r][2]=e2/s;
        }
      }
      __syncthreads();

      // ---- R3: usage update (tid<256) + write-content partials (all) ----
      if (tid < 256){
        int m = tid;
        float us = S.usage[m] + (1.0f - S.usage[m])*S.ww_[m];
        float psi = (1.0f - S.fg_[0]*S.rw_[0][m]) * (1.0f - S.fg_[1]*S.rw_[1][m])
                  * (1.0f - S.fg_[2]*S.rw_[2][m]) * (1.0f - S.fg_[3]*S.rw_[3][m]);
        us *= psi;
        S.usage[m] = us;
        S.uu[m] = DELTA_ + (1.0f - DELTA_)*us;
      }
      { float acc = 0.0f;
        #pragma unroll
        for (int it = 0; it < 32; ++it){
          int w = q2*32 + it;
          acc += S.smem[mH][w] * S.wkn[w];
        }
        S.p2cT[q2][mH] = acc; }
      __syncthreads();

      // ---- R4: wave0: wcw combine + softmax ; waves 4-7: rank-sort ----
      if (wv == 0){
        #pragma unroll
        for (int z = 0; z < 4; ++z){
          int m = z*64 + lane;
          S.wcw[m] = S.wsS * (S.p2cT[0][m] + S.p2cT[1][m]) * S.invn[m];
        }
        softmax256_wave(S.wcw, lane);
      } else if (tid >= 256){
        const int i = tid - 256;
        const float ui = S.uu[i];
        int cnt = 0;
        #pragma unroll 8
        for (int k = 0; k < 64; ++k){
          f32x4 u4 = *(const f32x4*)&S.uu[k*4];
          #pragma unroll
          for (int z = 0; z < 4; ++z){
            int j = k*4 + z; float uj = u4[z];
            cnt += (uj < ui || (uj == ui && j < i)) ? 1 : 0;
          }
        }
        S.rank_[i] = cnt;
        S.su[cnt] = ui;
      }
      __syncthreads();

      // ---- R5: exclusive product scan of su -> scanA (wave 0) ----
      if (wv == 0){
        int base = lane*4;
        float v0 = S.su[base], v1 = S.su[base+1], v2 = S.su[base+2];
        float p1 = v0*v1, p2 = p1*v2, p3 = p2*S.su[base+3];
        float sc = p3;
        #pragma unroll
        for (int off = 1; off < 64; off <<= 1){
          float n = __shfl_up(sc, off, 64);
          if (lane >= off) sc *= n;
        }
        float exch = __shfl_up(sc, 1, 64);
        if (lane == 0) exch = 1.0f;
        S.scanA[base] = exch; S.scanA[base+1] = exch*v0;
        S.scanA[base+2] = exch*p1; S.scanA[base+3] = exch*p2;
      }
      __syncthreads();

      // ---- R7: ww (redundant per half) + mem erase/write + partials ----
      { const int m = mH;
        float al = (1.0f - S.uu[m]) * S.scanA[S.rank_[m]];
        float wm = S.wgS*(S.agS*al + (1.0f - S.agS)*S.wcw[m]);
        if (q2 == 0){ S.ww_[m] = wm; S.wwb[m] = (bf16_t)wm; }
        float s2 = 0.0f, sr0 = 0.0f, sr1 = 0.0f, sr2 = 0.0f, sr3 = 0.0f;
        #pragma unroll
        for (int it = 0; it < 32; ++it){
          int w = q2*32 + it;
          float mn = S.smem[m][w]*(1.0f - wm*S.ev_[w]) + wm*S.wvv[w];
          S.smem[m][w] = mn;
          s2 += mn*mn;
          f32x4 rk = *(const f32x4*)&S.rkn4r[q2][w][0];
          sr0 += mn*rk[0]; sr1 += mn*rk[1]; sr2 += mn*rk[2]; sr3 += mn*rk[3];
        }
        S.p5cT[0][q2][m] = s2;
        S.p5cT[1][q2][m] = sr0; S.p5cT[2][q2][m] = sr1;
        S.p5cT[3][q2][m] = sr2; S.p5cT[4][q2][m] = sr3; }
      __syncthreads();

      // ---- R8: norm + read-content pre-softmax (tid<256); wave4: wwsum ----
      if (tid < 256){
        int m = tid;
        float s2 = S.p5cT[0][0][m] + S.p5cT[0][1][m];
        float inv = 1.0f/(sqrtf(s2) + DELTA_);
        S.invn[m] = inv;
        #pragma unroll
        for (int r = 0; r < 4; ++r){
          float sr = S.p5cT[r+1][0][m] + S.p5cT[r+1][1][m];
          S.rcw_[r][m] = S.rs_[r]*sr*inv;
        }
      } else if (wv == 4){
        float s = wred(S.ww_[lane] + S.ww_[64+lane] + S.ww_[128+lane] + S.ww_[192+lane]);
        if (lane == 0) S.wwsumS = s;
      }
      __syncthreads();

      // ---- R9: link update + fwd/bwd via MFMA ----
      { float wown[2], pown[2], alpha[2];
        #pragma unroll
        for (int g = 0; g < 2; ++g){
          int o = wv*32 + g*16 + li;
          wown[g] = (float)S.wwb[o]; pown[g] = (float)S.precb[o];
          alpha[g] = 1.0f - wown[g];
        }
        f32x4 facc[2] = {{0,0,0,0},{0,0,0,0}}, bacc[2] = {{0,0,0,0},{0,0,0,0}};
        #pragma unroll
        for (int ch = 0; ch < 8; ++ch){
          const int cbase = ch*32 + quad*8;
          bf16x8 rwf = *(const bf16x8*)&S.rwb[li & 3][cbase];
          bf16x8 wwv = *(const bf16x8*)&S.wwb[cbase];
          bf16x8 pcv = *(const bf16x8*)&S.precb[cbase];
          float wcf[8], pcf[8];
          #pragma unroll
          for (int jj = 0; jj < 8; ++jj){ wcf[jj] = (float)wwv[jj]; pcf[jj] = (float)pcv[jj]; }
          #pragma unroll
          for (int g = 0; g < 2; ++g){
            const int o = wv*32 + g*16 + li;
            bf16x8 rl = rowL[g][ch];
            bf16x8 cl = colL[g][ch];
            #pragma unroll
            for (int jj = 0; jj < 8; ++jj){
              const int c = cbase + jj;
              float s = alpha[g] - wcf[jj];
              float vr = s*(float)rl[jj] + wown[g]*pcf[jj];
              float vc = s*(float)cl[jj] + wcf[jj]*pown[g];
              if (c == o){ vr = 0.0f; vc = 0.0f; }
              rl[jj] = (bf16_t)vr;
              cl[jj] = (bf16_t)vc;
            }
            rowL[g][ch] = rl; colL[g][ch] = cl;
            facc[g] = __builtin_amdgcn_mfma_f32_16x16x32_bf16(rl, rwf, facc[g], 0, 0, 0);
            bacc[g] = __builtin_amdgcn_mfma_f32_16x16x32_bf16(rwf, cl, bacc[g], 0, 0, 0);
          }
        }
        #pragma unroll
        for (int g = 0; g < 2; ++g){
          if (li < 4){
            #pragma unroll
            for (int z = 0; z < 4; ++z) S.fwd_[li][wv*32 + g*16 + quad*4 + z] = facc[g][z];
          }
          if (quad == 0){
            #pragma unroll
            for (int z = 0; z < 4; ++z) S.bwd_[z][wv*32 + g*16 + li] = bacc[g][z];
          }
        }
      }
      __syncthreads();

      // ---- R10: waves0-3: rcw softmax ; waves4-7: precedence ----
      if (wv < 4) softmax256_wave(S.rcw_[wv], lane);
      else {
        int m = tid - 256;
        float p = (1.0f - S.wwsumS)*S.prec_[m] + S.ww_[m];
        S.prec_[m] = p;
        S.precb[m] = (bf16_t)p;
      }
      __syncthreads();

      // ---- R11: new read weights ----
      { int r = tid >> 7, m0 = (tid & 127)*2;
        #pragma unroll
        for (int z = 0; z < 2; ++z){
          int m = m0 + z;
          float v = S.rm_[r][0]*S.bwd_[r][m] + S.rm_[r][1]*S.fwd_[r][m] + S.rm_[r][2]*S.rcw_[r][m];
          S.rw_[r][m] = v;
          S.rw4[m][r] = v;
          S.rwb[r][m] = (bf16_t)v;
        } }
      __syncthreads();

      // ---- R12: read vectors: wave-per-32-rows ----
      { float r0 = 0, r1 = 0, r2 = 0, r3 = 0;
        #pragma unroll
        for (int k = 0; k < 32; ++k){
          int m = wv*32 + k;
          f32x4 r4 = *(const f32x4*)&S.rw4[m][0];
          float mv = S.smem[m][lane];
          r0 += r4[0]*mv; r1 += r4[1]*mv; r2 += r4[2]*mv; r3 += r4[3]*mv;
        }
        S.rvp[wv][0][lane] = r0; S.rvp[wv][1][lane] = r1;
        S.rvp[wv][2][lane] = r2; S.rvp[wv][3][lane] = r3; }
      __syncthreads();

      // ---- R13: combine + store ----
      if (tid < 256){
        const int w = tid & 63, r = tid >> 6;
        float v = 0.0f;
        #pragma unroll
        for (int c = 0; c < 8; ++c) v += S.rvp[c][r][w];
        RVEC[((size_t)t*64 + b)*256 + tid] = v;
      }
      __syncthreads();
    }
  }
}

// ---------------------------------------------------------------------------
__global__ void k_tanhy(const bf16_t* __restrict__ outseq, const float* __restrict__ RVEC,
                        bf16_t* __restrict__ Y){
  const int n = 2048*768;
  for (int i = blockIdx.x*blockDim.x + threadIdx.x; i < n; i += gridDim.x*blockDim.x){
    int row = i / 768, j = i - row*768;
    float v = (j < 512) ? (float)outseq[(size_t)row*512 + j] : RVEC[(size_t)row*256 + (j - 512)];
    Y[i] = (bf16_t)tanhf(v);
  }
}

__global__ __launch_bounds__(256,1) void k_out(
    const bf16_t* __restrict__ Y, const bf16_t* __restrict__ Woutb,
    const float* __restrict__ boutf, void* __restrict__ dout,
    const int* __restrict__ flag)
{
  const int mf = *flag;
  const int mt = blockIdx.x;          // 0..127
  const int tid = threadIdx.x, lane = tid & 63, wv = tid >> 6;
  const int nt = blockIdx.y*4 + wv;   // 0..15
  const int m16 = lane & 15, q = lane >> 4;
  const int o = nt*16 + m16;
  float bv = boutf[o];
  f32x4 acc = {bv,bv,bv,bv};
  const bf16_t* arow = Y + (size_t)(mt*16 + m16)*768 + q*8;
  const bf16_t* brow = Woutb + (size_t)o*768 + q*8;
  for (int kt = 0; kt < 24; ++kt){
    acc = __builtin_amdgcn_mfma_f32_16x16x32_bf16(
        *(const bf16x8*)(arow + kt*32), *(const bf16x8*)(brow + kt*32), acc, 0, 0, 0);
  }
  #pragma unroll
  for (int v = 0; v < 4; ++v){
    int row = mt*16 + q*4 + v;        // = t*64 + b
    int b = row & 63, t = row >> 6;
    size_t idx = ((size_t)b*T_ + t)*256 + o;
    if (mf) ((float*)dout)[idx] = acc[v];
    else    ((bf16_t*)dout)[idx] = (bf16_t)acc[v];
  }
}

// ---------------------------------------------------------------------------
extern "C" void kernel_launch(void* const* d_in, const int* in_sizes, int n_in,
                              void* d_out, int out_size, void* d_ws, size_t ws_size,
                              hipStream_t stream)
{
  char* ws = (char*)d_ws;
  bf16_t* H0SEQ  = (bf16_t*)(ws + OFF_H0SEQ);
  bf16_t* OUTSEQ = (bf16_t*)(ws + OFF_OUTSEQ);
  bf16_t* H0BUF  = (bf16_t*)(ws + OFF_H0BUF);
  bf16_t* H1BUF  = (bf16_t*)(ws + OFF_H1BUF);
  float*  XI     = (float*) (ws + OFF_XI);
  float*  RVEC   = (float*) (ws + OFF_RVEC);
  bf16_t* YBF    = (bf16_t*)(ws + OFF_YBF);
  unsigned* BAR  = (unsigned*)(ws + OFF_BAR);
  int*    FLAG   = (int*)   (ws + OFF_BAR + 8);
  bf16_t* XB     = (bf16_t*)(ws + OFF_XB);
  bf16_t* H0B    = (bf16_t*)(ws + OFF_H0B);
  bf16_t* W0     = (bf16_t*)(ws + OFF_W0);
  bf16_t* W1     = (bf16_t*)(ws + OFF_W1);
  bf16_t* W2     = (bf16_t*)(ws + OFF_W2);
  bf16_t* W3     = (bf16_t*)(ws + OFF_W3);
  bf16_t* WIFP   = (bf16_t*)(ws + OFF_WIF);
  bf16_t* WOUTB  = (bf16_t*)(ws + OFF_WOUTB);
  float*  BS0    = (float*) (ws + OFF_BS0);
  float*  BS1    = (float*) (ws + OFF_BS1);
  float*  BIFP   = (float*) (ws + OFF_BIF);
  float*  BOUTF  = (float*) (ws + OFF_BOUTF);

  k_detect<<<1, 256, 0, stream>>>((const unsigned short*)d_in[0], FLAG, BAR);
  k_convert<<<dim3(256, 9), 256, 0, stream>>>(
      d_in[0], d_in[1], d_in[2], d_in[3], d_in[4], d_in[5], d_in[6],
      d_in[7], d_in[8], d_in[9], d_in[10], d_in[11], d_in[12], d_in[13],
      XB, H0B, H0BUF, H1BUF, W0, W1, W2, W3, WIFP, WOUTB,
      BS0, BS1, BIFP, BOUTF, FLAG);
  k_main<<<128, 512, 0, stream>>>(XB, H0B, W0, W1, W2, W3, BS0, BS1,
                                  WIFP, BIFP, H0BUF, H1BUF, H0SEQ, OUTSEQ,
                                  XI, RVEC, BAR);
  k_tanhy<<<512, 256, 0, stream>>>(OUTSEQ, RVEC, YBF);
  k_out<<<dim3(128, 4), 256, 0, stream>>>(YBF, WOUTB, BOUTF, d_out, FLAG);
}